// Round 16
// baseline (199.239 us; speedup 1.0000x reference)
//
#include <hip/hip_runtime.h>
#include <math.h>

#define CAT    134
#define NRBF   6
#define ADIM   42
#define NBIL   8
#define KPAD   144      // 9 k-steps of 16 (k=134 is the bias column)
#define CHPAD  160      // 5 groups x 32 channels
#define MSTR   152      // m LDS row stride (shorts): 304 B, 16B-aligned
#define TSTR   168      // mae row stride (shorts): 336 B, 16B-aligned
#define TE     32       // edges per tile
#define M2     (TE * 67)   // float2 count of one m tile (32*134/2)

typedef __bf16 bf16x8 __attribute__((ext_vector_type(8)));
typedef float  f32x16 __attribute__((ext_vector_type(16)));
typedef float  f32x4  __attribute__((ext_vector_type(4)));

__device__ __forceinline__ unsigned short f32_bf16_rne(float x) {
    union { float f; unsigned u; } v; v.f = x;
    unsigned u = v.u;
    u += 0x7FFFu + ((u >> 16) & 1u);
    return (unsigned short)(u >> 16);
}
__device__ __forceinline__ float bf16_f32(unsigned short h) {
    union { float f; unsigned u; } v; v.u = ((unsigned)h) << 16;
    return v.f;
}
// trunc split: a = hi + lo, |err| ~ 2^-17 |a|  (used for DATA: m, e_rbf)
__device__ __forceinline__ void split_pack(float a, float b, unsigned& ph, unsigned& pl) {
    unsigned ua = __float_as_uint(a), ub = __float_as_uint(b);
    ph = (ua >> 16) | (ub & 0xffff0000u);
    float ra = a - __uint_as_float(ua & 0xffff0000u);
    float rb = b - __uint_as_float(ub & 0xffff0000u);
    pl = (__float_as_uint(ra) >> 16) | (__float_as_uint(rb) & 0xffff0000u);
}
// RNE pack of two floats to bf16 pair (for mae)
__device__ __forceinline__ unsigned rne_pack(float a, float b) {
    return (unsigned)f32_bf16_rne(a) | ((unsigned)f32_bf16_rne(b) << 16);
}
__device__ __forceinline__ bf16x8 upack(unsigned a, unsigned b, unsigned c, unsigned d) {
    union { unsigned u[4]; bf16x8 v; } t;
    t.u[0] = a; t.u[1] = b; t.u[2] = c; t.u[3] = d;
    return t.v;
}

// ---------------------------------------------------------------------------
// prep: pack weights into FRAGMENT-MAJOR layout (hi+lo; kernel reads hi only)
// ---------------------------------------------------------------------------
__global__ __launch_bounds__(256) void prep_kernel(
    const float* __restrict__ Wm, const float* __restrict__ bm,
    const float* __restrict__ We, const float* __restrict__ fw,
    unsigned short* __restrict__ WF, unsigned short* __restrict__ WeF,
    unsigned short* __restrict__ FwF)
{
    int i = blockIdx.x * 256 + threadIdx.x;
    if (i < CHPAD * KPAD) {                                  // W_m (+bias col)
        int c = i / KPAD, k = i - c * KPAD;
        float v = 0.f;
        if (c < CAT) {
            if (k < CAT) v = Wm[c * CAT + k];
            else if (k == CAT) v = bm[c];
        }
        unsigned short h = f32_bf16_rne(v);
        unsigned short l = f32_bf16_rne(v - bf16_f32(h));
        int wv = c >> 5, l31 = c & 31, ks = k >> 4;
        int lane = ((k >> 3) & 1) * 32 + l31, j = k & 7;
        size_t idx = ((size_t)(wv * 9 + ks) * 64 + lane) * 16 + j;
        WF[idx] = h; WF[idx + 8] = l;
    } else if (i < CHPAD * KPAD + CHPAD * 16) {              // W_e (K -> 16)
        int j2 = i - CHPAD * KPAD; int c = j2 >> 4, r = j2 & 15;
        float v = (c < CAT && r < NRBF) ? We[c * NRBF + r] : 0.f;
        unsigned short h = f32_bf16_rne(v);
        unsigned short l = f32_bf16_rne(v - bf16_f32(h));
        int wv = c >> 5, l31 = c & 31;
        int lane = (r >> 3) * 32 + l31, j = r & 7;
        size_t idx = ((size_t)wv * 64 + lane) * 16 + j;
        WeF[idx] = h; WeF[idx + 8] = l;
    } else if (i < CHPAD * KPAD + CHPAD * 16 + 16 * CHPAD) { // final_w (16 rows)
        int j3 = i - CHPAD * KPAD - CHPAD * 16;
        int r = j3 / CHPAD, c = j3 - r * CHPAD;
        float v = (r < NRBF && c < CAT) ? fw[r * CAT + c] : 0.f;
        unsigned short h = f32_bf16_rne(v);
        unsigned short l = f32_bf16_rne(v - bf16_f32(h));
        int wv = c >> 5, kk = c & 31;
        int lane = (kk >> 3) * 16 + r, j = kk & 7;
        size_t idx = ((size_t)wv * 64 + lane) * 16 + j;
        FwF[idx] = h; FwF[idx + 8] = l;
    }
}

// ---------------------------------------------------------------------------
// angle: s_a = dot(a_sbf[a,:], colsum(W_a)), scatter-add into sum_s[kj]
// ---------------------------------------------------------------------------
__global__ __launch_bounds__(256) void angle_kernel(
    const float* __restrict__ a_sbf, const int* __restrict__ kj_idx,
    const float* __restrict__ W_a, float* __restrict__ sum_s, int A)
{
    __shared__ float wsum[ADIM];
    int tid = threadIdx.x;
    if (tid < ADIM) {
        float s = 0.f;
        #pragma unroll
        for (int b = 0; b < NBIL; ++b) s += W_a[b * ADIM + tid];
        wsum[tid] = s;
    }
    __syncthreads();

    int a = blockIdx.x * 256 + tid;
    if (a >= A) return;

    const float* row = a_sbf + (size_t)a * ADIM;
    float s = 0.f;
    #pragma unroll
    for (int d2 = 0; d2 < ADIM / 2; ++d2) {
        float2 v = *reinterpret_cast<const float2*>(row + d2 * 2);
        s += v.x * wsum[d2 * 2] + v.y * wsum[d2 * 2 + 1];
    }
    atomicAdd(&sum_s[kj_idx[a]], s);
}

// Zero-instruction opaque pin: hi-only weight set (44 VGPRs).
#define PIN_WEIGHTS()                                                          \
    asm volatile("" :                                                         \
        "+v"(wfh[0]), "+v"(wfh[1]), "+v"(wfh[2]), "+v"(wfh[3]), "+v"(wfh[4]), \
        "+v"(wfh[5]), "+v"(wfh[6]), "+v"(wfh[7]), "+v"(wfh[8]),               \
        "+v"(weh), "+v"(fwh))

#define MF32(AC, W, B) AC = __builtin_amdgcn_mfma_f32_32x32x16_bf16(W, B, AC, 0, 0, 0)

// ---------------------------------------------------------------------------
// edge: R15 structure (hi-only weights, 4 waves, LDS 39.4 KB) with the
// register allocator PINNED to the 128-reg bucket via amdgpu_waves_per_eu(4,4)
// -- R15's compiler chose the 64-reg bucket and spilled mpre to scratch
// (WRITE_SIZE 9->34 MB, FETCH +93 MB). 2 barriers/tile, grid 2048.
// ---------------------------------------------------------------------------
__global__ __launch_bounds__(256)
__attribute__((amdgpu_waves_per_eu(4, 4)))
void edge_kernel(
    const float* __restrict__ m_ji, const float* __restrict__ e_rbf,
    const float* __restrict__ We_raw,
    const unsigned short* __restrict__ WF, const unsigned short* __restrict__ WeF,
    const unsigned short* __restrict__ FwF,
    const float* __restrict__ sum_s, float* __restrict__ out, int E, int NT)
{
    __shared__ unsigned short mhs[TE][MSTR];    //  9728 B
    __shared__ unsigned short mls[TE][MSTR];    //  9728 B
    __shared__ unsigned short maeh[TE][TSTR];   // 10752 B (proj overlaid)
    __shared__ unsigned short wf4s[9][64][8];   //  9216 B  -> 39424 B total

    const int tid = threadIdx.x;
    const int l   = tid & 63;
    const int wv  = __builtin_amdgcn_readfirstlane(tid >> 6);  // 0..3
    const int l31 = l & 31;
    const int hi5 = l >> 5;
    const int GD  = gridDim.x;

    // ---- resident HI weight fragments for this wave's main group ---------
    bf16x8 wfh[9];
    #pragma unroll
    for (int ks = 0; ks < 9; ++ks)
        wfh[ks] = *reinterpret_cast<const bf16x8*>(WF + ((size_t)(wv * 9 + ks) * 64 + l) * 16);
    bf16x8 weh = *reinterpret_cast<const bf16x8*>(WeF + ((size_t)wv * 64 + l) * 16);
    bf16x8 fwh = *reinterpret_cast<const bf16x8*>(FwF + ((size_t)wv * 64 + l) * 16);
    PIN_WEIGHTS();

    // ---- stage tail group-4 HI A-fragments into LDS (once) ---------------
    {
        for (int f = tid; f < 9 * 64; f += 256) {   // 576 x 16B (hi half only)
            int ks = f / 64, ln = f - ks * 64;
            const uint4* src = reinterpret_cast<const uint4*>(
                WF + ((size_t)(4 * 9 + ks) * 64 + ln) * 16);
            *reinterpret_cast<uint4*>(&wf4s[ks][ln][0]) = src[0];
        }
    }

    // ---- wave-uniform W_e scalars for tail te (rows 128..133) -> SGPRs ---
    float we4[6][6];
    #pragma unroll
    for (int r0 = 0; r0 < 6; ++r0)
        #pragma unroll
        for (int r = 0; r < 6; ++r)
            we4[r0][r] = We_raw[(size_t)(128 + r0) * NRBF + r];

    // ---- one-time LDS init: m bias/pad cols 134..143 ---------------------
    if (tid < 160) {
        int r = tid / 5, j = tid - r * 5;
        *reinterpret_cast<unsigned*>(&mhs[r][134 + 2 * j]) = (j == 0) ? 0x00003F80u : 0u;
        *reinterpret_cast<unsigned*>(&mls[r][134 + 2 * j]) = 0u;
    }

    // ---- per-lane prefetch state -----------------------------------------
    float2 mpre[9];
    float2 er01, er23, er45;
    float  ssp;

#define LOADM(T)                                                              \
    do { int tt = (T);                                                        \
        const float2* mb = reinterpret_cast<const float2*>(m_ji + (size_t)tt * TE * CAT); \
        int nv2 = min(TE, E - tt * TE) * 67;                                  \
        _Pragma("unroll")                                                     \
        for (int i_ = 0; i_ < 9; ++i_) {                                      \
            int f_ = tid + i_ * 256;                                          \
            mpre[i_] = (f_ < nv2) ? mb[f_] : make_float2(0.f, 0.f);           \
        }                                                                     \
    } while (0)

#define LOADE(T)                                                              \
    do { int tt = (T);                                                        \
        er01 = make_float2(0.f, 0.f); er23 = er01; er45 = er01;               \
        int e_ = tt * TE + l31;                                               \
        if (e_ < E) {                                                         \
            const float* ep_ = e_rbf + (size_t)e_ * NRBF;                     \
            er01 = *reinterpret_cast<const float2*>(ep_);                     \
            er23 = *reinterpret_cast<const float2*>(ep_ + 2);                 \
            er45 = *reinterpret_cast<const float2*>(ep_ + 4);                 \
        }                                                                     \
    } while (0)

#define LOADSS(T)                                                             \
    do { int tt = (T);                                                        \
        ssp = 0.f;                                                            \
        if (tid < 192) {                                                      \
            int eo_ = tt * TE + tid / 6;                                      \
            if (eo_ < E) ssp = sum_s[eo_];                                    \
        }                                                                     \
    } while (0)

    // ---- prologue: prefetch tile t0 ---------------------------------------
    {
        int t0 = blockIdx.x;
        LOADM(t0); LOADE(t0); LOADSS(t0);
    }

    int it = 0;
    for (int t = blockIdx.x; t < NT; t += GD, ++it) {
        const int e0 = t * TE;
        PIN_WEIGHTS();

        // ---- latch this tile's er (tail te) + ss; build eb frags ---------
        float er_s0 = er01.x, er_s1 = er01.y, er_s2 = er23.x,
              er_s3 = er23.y, er_s4 = er45.x, er_s5 = er45.y;
        const float ss_cur = ssp;
        bf16x8 ebh, ebl;
        {
            unsigned h0, h1, h2, q0, q1, q2;
            split_pack(er01.x, er01.y, h0, q0);
            split_pack(er23.x, er23.y, h1, q1);
            split_pack(er45.x, er45.y, h2, q2);
            if (hi5) { h0 = h1 = h2 = q0 = q1 = q2 = 0; }   // k 8..15 pad
            ebh = upack(h0, h1, h2, 0);
            ebl = upack(q0, q1, q2, 0);
        }

        // ---- stage m tile -> split-bf16 LDS (once per value) -------------
        #pragma unroll
        for (int i = 0; i < 9; ++i) {
            int f = tid + i * 256;
            if (f < M2) {
                int r = f / 67, c = f - r * 67;
                unsigned h, lo2; split_pack(mpre[i].x, mpre[i].y, h, lo2);
                *reinterpret_cast<unsigned*>(&mhs[r][2 * c]) = h;
                *reinterpret_cast<unsigned*>(&mls[r][2 * c]) = lo2;
            }
        }
        __syncthreads();   // barrier A: tile staged

        // ---- issue next tile's global loads (ride under MFMA) ------------
        if (t + GD < NT) { LOADM(t + GD); LOADE(t + GD); LOADSS(t + GD); }

        // ---- MFMA1 main: x = Wh.(mh+ml) (+bias), 18 MFMAs ----------------
        f32x16 acc  = {0,0,0,0,0,0,0,0,0,0,0,0,0,0,0,0};
        f32x16 acct = {0,0,0,0,0,0,0,0,0,0,0,0,0,0,0,0};
        #pragma unroll
        for (int ks = 0; ks < 9; ++ks) {
            bf16x8 bh = *reinterpret_cast<const bf16x8*>(&mhs[l31][ks * 16 + hi5 * 8]);
            bf16x8 bl = *reinterpret_cast<const bf16x8*>(&mls[l31][ks * 16 + hi5 * 8]);
            MF32(acc, wfh[ks], bh);
            MF32(acc, wfh[ks], bl);
        }
        MF32(acct, weh, ebh);
        MF32(acct, weh, ebl);

        // ---- mae = silu(x)*te -> RNE bf16 -> wave-private LDS slice ------
        #pragma unroll
        for (int q = 0; q < 4; ++q) {
            float mz[4];
            #pragma unroll
            for (int i = 0; i < 4; ++i) {
                float x  = acc[q * 4 + i];
                float sg = x / (1.f + __expf(-x));
                mz[i] = sg * acct[q * 4 + i];
            }
            const int cq = 32 * wv + 8 * q + 4 * hi5;
            *reinterpret_cast<uint2*>(&maeh[l31][cq]) =
                make_uint2(rne_pack(mz[0], mz[1]), rne_pack(mz[2], mz[3]));
        }

        // ---- MFMA3 main: own slice -> overlay [es][32wv..], 1 MFMA/nt ----
        #pragma unroll
        for (int nt = 0; nt < 2; ++nt) {
            f32x4 a3 = {0, 0, 0, 0};
            const int mr = nt * 16 + (l & 15);
            bf16x8 bh = *reinterpret_cast<const bf16x8*>(&maeh[mr][32 * wv + (l >> 4) * 8]);
            a3 = __builtin_amdgcn_mfma_f32_16x16x32_bf16(fwh, bh, a3, 0, 0, 0);
            const int g4 = l >> 4, es = nt * 16 + (l & 15);
            if (g4 == 0) {
                *reinterpret_cast<f32x4*>(&maeh[es][32 * wv]) = a3;
            } else if (g4 == 1) {
                *reinterpret_cast<float*>(&maeh[es][32 * wv + 8])  = a3[0];
                *reinterpret_cast<float*>(&maeh[es][32 * wv + 10]) = a3[1];
            }
        }

        // ---- TAIL group 4 (channels 128-133), one rotating wave ----------
        if (wv == ((blockIdx.x + it) & 3)) {
            const unsigned short* pf4 = FwF + ((size_t)4 * 64 + l) * 16;
            bf16x8 fw4h = *reinterpret_cast<const bf16x8*>(pf4);

            f32x16 acc4 = {0,0,0,0,0,0,0,0,0,0,0,0,0,0,0,0};
            #pragma unroll
            for (int ks = 0; ks < 9; ++ks) {   // A-frags from LDS (pipelined)
                bf16x8 a4h = *reinterpret_cast<const bf16x8*>(&wf4s[ks][l][0]);
                bf16x8 bh = *reinterpret_cast<const bf16x8*>(&mhs[l31][ks * 16 + hi5 * 8]);
                bf16x8 bl = *reinterpret_cast<const bf16x8*>(&mls[l31][ks * 16 + hi5 * 8]);
                MF32(acc4, a4h, bh);
                MF32(acc4, a4h, bl);
            }
            // te4 in fp32 VALU: reg i covers row (i&3)+8(i>>2)+4hi5
            float te4[4];
            #pragma unroll
            for (int i = 0; i < 4; ++i) {
                float dlo = er_s0 * we4[i][0] + er_s1 * we4[i][1] + er_s2 * we4[i][2]
                          + er_s3 * we4[i][3] + er_s4 * we4[i][4] + er_s5 * we4[i][5];
                float dhi = 0.f;
                if (i < 2)
                    dhi = er_s0 * we4[4 + i][0] + er_s1 * we4[4 + i][1] + er_s2 * we4[4 + i][2]
                        + er_s3 * we4[4 + i][3] + er_s4 * we4[4 + i][4] + er_s5 * we4[4 + i][5];
                te4[i] = hi5 ? dhi : dlo;
            }
            // mae4 (hi only; rows 0-5 live in q==0 regs)
            {
                float mz[4];
                #pragma unroll
                for (int i = 0; i < 4; ++i) {
                    float sg = acc4[i] / (1.f + __expf(-acc4[i]));
                    mz[i] = sg * te4[i];
                }
                const int cq = 128 + 4 * hi5;
                *reinterpret_cast<uint2*>(&maeh[l31][cq]) =
                    make_uint2(rne_pack(mz[0], mz[1]), rne_pack(mz[2], mz[3]));
                #pragma unroll
                for (int q = 1; q < 4; ++q)
                    *reinterpret_cast<uint2*>(&maeh[l31][128 + 8 * q + 4 * hi5]) = make_uint2(0, 0);
            }
            // tail MFMA3 -> overlay [es][128..]
            #pragma unroll
            for (int nt = 0; nt < 2; ++nt) {
                f32x4 a3 = {0, 0, 0, 0};
                const int mr = nt * 16 + (l & 15);
                bf16x8 bh = *reinterpret_cast<const bf16x8*>(&maeh[mr][128 + (l >> 4) * 8]);
                a3 = __builtin_amdgcn_mfma_f32_16x16x32_bf16(fw4h, bh, a3, 0, 0, 0);
                const int g4 = l >> 4, es = nt * 16 + (l & 15);
                if (g4 == 0) {
                    *reinterpret_cast<f32x4*>(&maeh[es][128]) = a3;
                } else if (g4 == 1) {
                    *reinterpret_cast<float*>(&maeh[es][128 + 8])  = a3[0];
                    *reinterpret_cast<float*>(&maeh[es][128 + 10]) = a3[1];
                }
            }
        }
        __syncthreads();   // barrier B: all overlays complete

        // ---- cross-group reduce + scale + store --------------------------
        if (tid < 192) {
            const int es = tid / 6, r = tid - es * 6;
            const int eo = e0 + es;
            if (eo < E) {
                float vsum = 0.f;
                #pragma unroll
                for (int w2 = 0; w2 < 5; ++w2)
                    vsum += *reinterpret_cast<const float*>(&maeh[es][32 * w2 + 2 * r]);
                out[(size_t)eo * NRBF + r] = vsum * ss_cur;
            }
        }
    }
#undef LOADM
#undef LOADE
#undef LOADSS
}

// ---------------------------------------------------------------------------
extern "C" void kernel_launch(void* const* d_in, const int* in_sizes, int n_in,
                              void* d_out, int out_size, void* d_ws, size_t ws_size,
                              hipStream_t stream)
{
    const float* m_ji    = (const float*)d_in[0];
    // d_in[1] nbr_list, d_in[2] angle_list: unused by the reference math
    const float* e_rbf   = (const float*)d_in[3];
    const float* a_sbf   = (const float*)d_in[4];
    const int*   kj_idx  = (const int*)  d_in[5];
    const float* W_m     = (const float*)d_in[6];
    const float* b_m     = (const float*)d_in[7];
    const float* W_e     = (const float*)d_in[8];
    const float* W_a     = (const float*)d_in[9];
    const float* final_w = (const float*)d_in[10];
    float* out = (float*)d_out;

    const int E  = in_sizes[0] / CAT;
    const int A  = in_sizes[5];
    const int NT = (E + TE - 1) / TE;

    // workspace layout
    char* ws = (char*)d_ws;
    float* sum_s = (float*)ws;
    size_t off = ((size_t)E * 4 + 255) & ~(size_t)255;
    unsigned short* WF  = (unsigned short*)(ws + off); off += (size_t)5 * 9 * 64 * 16 * 2;
    unsigned short* WeF = (unsigned short*)(ws + off); off += (size_t)5 * 64 * 16 * 2;
    unsigned short* FwF = (unsigned short*)(ws + off); off += (size_t)5 * 64 * 16 * 2;

    hipMemsetAsync(sum_s, 0, (size_t)E * sizeof(float), stream);

    const int prep_n = CHPAD * KPAD + CHPAD * 16 + 16 * CHPAD;
    prep_kernel<<<(prep_n + 255) / 256, 256, 0, stream>>>(
        W_m, b_m, W_e, final_w, WF, WeF, FwF);
    angle_kernel<<<(A + 255) / 256, 256, 0, stream>>>(a_sbf, kj_idx, W_a, sum_s, A);

    int grid = 2048; if (grid > NT) grid = NT;
    edge_kernel<<<grid, 256, 0, stream>>>(m_ji, e_rbf, W_e, WF, WeF, FwF,
                                          sum_s, out, E, NT);
}

// Round 17
// 141.635 us; speedup vs baseline: 1.4067x; 1.4067x over previous
//
#include <hip/hip_runtime.h>
#include <math.h>

#define CAT    134
#define NRBF   6
#define ADIM   42
#define NBIL   8
#define KPAD   144      // 9 k-steps of 16 (k=134 is the bias column)
#define CHPAD  160      // 5 groups x 32 channels
#define MSTR   152      // m LDS row stride (shorts): 304 B, 16B-aligned
#define TSTR   168      // mae row stride (shorts): 336 B, 16B-aligned
#define TE     32       // edges per tile
#define M2     (TE * 67)   // float2 count of one m tile (32*134/2)

typedef __bf16 bf16x8 __attribute__((ext_vector_type(8)));
typedef float  f32x16 __attribute__((ext_vector_type(16)));
typedef float  f32x4  __attribute__((ext_vector_type(4)));

__device__ __forceinline__ unsigned short f32_bf16_rne(float x) {
    union { float f; unsigned u; } v; v.f = x;
    unsigned u = v.u;
    u += 0x7FFFu + ((u >> 16) & 1u);
    return (unsigned short)(u >> 16);
}
__device__ __forceinline__ float bf16_f32(unsigned short h) {
    union { float f; unsigned u; } v; v.u = ((unsigned)h) << 16;
    return v.f;
}
// trunc split: a = hi + lo, |err| ~ 2^-17 |a|  (used for DATA: m, e_rbf)
__device__ __forceinline__ void split_pack(float a, float b, unsigned& ph, unsigned& pl) {
    unsigned ua = __float_as_uint(a), ub = __float_as_uint(b);
    ph = (ua >> 16) | (ub & 0xffff0000u);
    float ra = a - __uint_as_float(ua & 0xffff0000u);
    float rb = b - __uint_as_float(ub & 0xffff0000u);
    pl = (__float_as_uint(ra) >> 16) | (__float_as_uint(rb) & 0xffff0000u);
}
// RNE pack of two floats to bf16 pair (for mae)
__device__ __forceinline__ unsigned rne_pack(float a, float b) {
    return (unsigned)f32_bf16_rne(a) | ((unsigned)f32_bf16_rne(b) << 16);
}
__device__ __forceinline__ bf16x8 upack(unsigned a, unsigned b, unsigned c, unsigned d) {
    union { unsigned u[4]; bf16x8 v; } t;
    t.u[0] = a; t.u[1] = b; t.u[2] = c; t.u[3] = d;
    return t.v;
}

// ---------------------------------------------------------------------------
// prep: pack weights into FRAGMENT-MAJOR layout (hi+lo; kernel reads hi only)
// ---------------------------------------------------------------------------
__global__ __launch_bounds__(256) void prep_kernel(
    const float* __restrict__ Wm, const float* __restrict__ bm,
    const float* __restrict__ We, const float* __restrict__ fw,
    unsigned short* __restrict__ WF, unsigned short* __restrict__ WeF,
    unsigned short* __restrict__ FwF)
{
    int i = blockIdx.x * 256 + threadIdx.x;
    if (i < CHPAD * KPAD) {                                  // W_m (+bias col)
        int c = i / KPAD, k = i - c * KPAD;
        float v = 0.f;
        if (c < CAT) {
            if (k < CAT) v = Wm[c * CAT + k];
            else if (k == CAT) v = bm[c];
        }
        unsigned short h = f32_bf16_rne(v);
        unsigned short l = f32_bf16_rne(v - bf16_f32(h));
        int wv = c >> 5, l31 = c & 31, ks = k >> 4;
        int lane = ((k >> 3) & 1) * 32 + l31, j = k & 7;
        size_t idx = ((size_t)(wv * 9 + ks) * 64 + lane) * 16 + j;
        WF[idx] = h; WF[idx + 8] = l;
    } else if (i < CHPAD * KPAD + CHPAD * 16) {              // W_e (K -> 16)
        int j2 = i - CHPAD * KPAD; int c = j2 >> 4, r = j2 & 15;
        float v = (c < CAT && r < NRBF) ? We[c * NRBF + r] : 0.f;
        unsigned short h = f32_bf16_rne(v);
        unsigned short l = f32_bf16_rne(v - bf16_f32(h));
        int wv = c >> 5, l31 = c & 31;
        int lane = (r >> 3) * 32 + l31, j = r & 7;
        size_t idx = ((size_t)wv * 64 + lane) * 16 + j;
        WeF[idx] = h; WeF[idx + 8] = l;
    } else if (i < CHPAD * KPAD + CHPAD * 16 + 16 * CHPAD) { // final_w (16 rows)
        int j3 = i - CHPAD * KPAD - CHPAD * 16;
        int r = j3 / CHPAD, c = j3 - r * CHPAD;
        float v = (r < NRBF && c < CAT) ? fw[r * CAT + c] : 0.f;
        unsigned short h = f32_bf16_rne(v);
        unsigned short l = f32_bf16_rne(v - bf16_f32(h));
        int wv = c >> 5, kk = c & 31;
        int lane = (kk >> 3) * 16 + r, j = kk & 7;
        size_t idx = ((size_t)wv * 64 + lane) * 16 + j;
        FwF[idx] = h; FwF[idx + 8] = l;
    }
}

// ---------------------------------------------------------------------------
// angle: s_a = dot(a_sbf[a,:], colsum(W_a)), scatter-add into sum_s[kj]
// ---------------------------------------------------------------------------
__global__ __launch_bounds__(256) void angle_kernel(
    const float* __restrict__ a_sbf, const int* __restrict__ kj_idx,
    const float* __restrict__ W_a, float* __restrict__ sum_s, int A)
{
    __shared__ float wsum[ADIM];
    int tid = threadIdx.x;
    if (tid < ADIM) {
        float s = 0.f;
        #pragma unroll
        for (int b = 0; b < NBIL; ++b) s += W_a[b * ADIM + tid];
        wsum[tid] = s;
    }
    __syncthreads();

    int a = blockIdx.x * 256 + tid;
    if (a >= A) return;

    const float* row = a_sbf + (size_t)a * ADIM;
    float s = 0.f;
    #pragma unroll
    for (int d2 = 0; d2 < ADIM / 2; ++d2) {
        float2 v = *reinterpret_cast<const float2*>(row + d2 * 2);
        s += v.x * wsum[d2 * 2] + v.y * wsum[d2 * 2 + 1];
    }
    atomicAdd(&sum_s[kj_idx[a]], s);
}

// Zero-instruction opaque pin: hi-only weight set (44 VGPRs).
#define PIN_WEIGHTS()                                                          \
    asm volatile("" :                                                         \
        "+v"(wfh[0]), "+v"(wfh[1]), "+v"(wfh[2]), "+v"(wfh[3]), "+v"(wfh[4]), \
        "+v"(wfh[5]), "+v"(wfh[6]), "+v"(wfh[7]), "+v"(wfh[8]),               \
        "+v"(weh), "+v"(fwh))

#define MF32(AC, W, B) AC = __builtin_amdgcn_mfma_f32_32x32x16_bf16(W, B, AC, 0, 0, 0)

// ---------------------------------------------------------------------------
// edge: R15 structure (hi-only weights, 4 waves, LDS 39.4 KB), register
// allocator targeted at EXACTLY 3 waves/EU (budget 512/3 = 170 unified regs:
// 64 acc-rounded + ~104 arch >= ~75 live pressure -> no spill). R15/R16's
// 4-waves budget (128) left only 64 arch VGPRs after acc rounding -> spills.
// 3 waves/SIMD = 12 waves/CU = 3 blocks/CU (+50% over R14). 2 barriers/tile.
// ---------------------------------------------------------------------------
__global__ __launch_bounds__(256)
__attribute__((amdgpu_waves_per_eu(3, 3)))
void edge_kernel(
    const float* __restrict__ m_ji, const float* __restrict__ e_rbf,
    const float* __restrict__ We_raw,
    const unsigned short* __restrict__ WF, const unsigned short* __restrict__ WeF,
    const unsigned short* __restrict__ FwF,
    const float* __restrict__ sum_s, float* __restrict__ out, int E, int NT)
{
    __shared__ unsigned short mhs[TE][MSTR];    //  9728 B
    __shared__ unsigned short mls[TE][MSTR];    //  9728 B
    __shared__ unsigned short maeh[TE][TSTR];   // 10752 B (proj overlaid)
    __shared__ unsigned short wf4s[9][64][8];   //  9216 B  -> 39424 B total

    const int tid = threadIdx.x;
    const int l   = tid & 63;
    const int wv  = __builtin_amdgcn_readfirstlane(tid >> 6);  // 0..3
    const int l31 = l & 31;
    const int hi5 = l >> 5;
    const int GD  = gridDim.x;

    // ---- resident HI weight fragments for this wave's main group ---------
    bf16x8 wfh[9];
    #pragma unroll
    for (int ks = 0; ks < 9; ++ks)
        wfh[ks] = *reinterpret_cast<const bf16x8*>(WF + ((size_t)(wv * 9 + ks) * 64 + l) * 16);
    bf16x8 weh = *reinterpret_cast<const bf16x8*>(WeF + ((size_t)wv * 64 + l) * 16);
    bf16x8 fwh = *reinterpret_cast<const bf16x8*>(FwF + ((size_t)wv * 64 + l) * 16);
    PIN_WEIGHTS();

    // ---- stage tail group-4 HI A-fragments into LDS (once) ---------------
    {
        for (int f = tid; f < 9 * 64; f += 256) {   // 576 x 16B (hi half only)
            int ks = f / 64, ln = f - ks * 64;
            const uint4* src = reinterpret_cast<const uint4*>(
                WF + ((size_t)(4 * 9 + ks) * 64 + ln) * 16);
            *reinterpret_cast<uint4*>(&wf4s[ks][ln][0]) = src[0];
        }
    }

    // ---- wave-uniform W_e scalars for tail te (rows 128..133) -> SGPRs ---
    float we4[6][6];
    #pragma unroll
    for (int r0 = 0; r0 < 6; ++r0)
        #pragma unroll
        for (int r = 0; r < 6; ++r)
            we4[r0][r] = We_raw[(size_t)(128 + r0) * NRBF + r];

    // ---- one-time LDS init: m bias/pad cols 134..143 ---------------------
    if (tid < 160) {
        int r = tid / 5, j = tid - r * 5;
        *reinterpret_cast<unsigned*>(&mhs[r][134 + 2 * j]) = (j == 0) ? 0x00003F80u : 0u;
        *reinterpret_cast<unsigned*>(&mls[r][134 + 2 * j]) = 0u;
    }

    // ---- per-lane prefetch state -----------------------------------------
    float2 mpre[9];
    float2 er01, er23, er45;
    float  ssp;

#define LOADM(T)                                                              \
    do { int tt = (T);                                                        \
        const float2* mb = reinterpret_cast<const float2*>(m_ji + (size_t)tt * TE * CAT); \
        int nv2 = min(TE, E - tt * TE) * 67;                                  \
        _Pragma("unroll")                                                     \
        for (int i_ = 0; i_ < 9; ++i_) {                                      \
            int f_ = tid + i_ * 256;                                          \
            mpre[i_] = (f_ < nv2) ? mb[f_] : make_float2(0.f, 0.f);           \
        }                                                                     \
    } while (0)

#define LOADE(T)                                                              \
    do { int tt = (T);                                                        \
        er01 = make_float2(0.f, 0.f); er23 = er01; er45 = er01;               \
        int e_ = tt * TE + l31;                                               \
        if (e_ < E) {                                                         \
            const float* ep_ = e_rbf + (size_t)e_ * NRBF;                     \
            er01 = *reinterpret_cast<const float2*>(ep_);                     \
            er23 = *reinterpret_cast<const float2*>(ep_ + 2);                 \
            er45 = *reinterpret_cast<const float2*>(ep_ + 4);                 \
        }                                                                     \
    } while (0)

#define LOADSS(T)                                                             \
    do { int tt = (T);                                                        \
        ssp = 0.f;                                                            \
        if (tid < 192) {                                                      \
            int eo_ = tt * TE + tid / 6;                                      \
            if (eo_ < E) ssp = sum_s[eo_];                                    \
        }                                                                     \
    } while (0)

    // ---- prologue: prefetch tile t0 ---------------------------------------
    {
        int t0 = blockIdx.x;
        LOADM(t0); LOADE(t0); LOADSS(t0);
    }

    int it = 0;
    for (int t = blockIdx.x; t < NT; t += GD, ++it) {
        const int e0 = t * TE;
        PIN_WEIGHTS();

        // ---- latch this tile's er (tail te) + ss; build eb frags ---------
        float er_s0 = er01.x, er_s1 = er01.y, er_s2 = er23.x,
              er_s3 = er23.y, er_s4 = er45.x, er_s5 = er45.y;
        const float ss_cur = ssp;
        bf16x8 ebh, ebl;
        {
            unsigned h0, h1, h2, q0, q1, q2;
            split_pack(er01.x, er01.y, h0, q0);
            split_pack(er23.x, er23.y, h1, q1);
            split_pack(er45.x, er45.y, h2, q2);
            if (hi5) { h0 = h1 = h2 = q0 = q1 = q2 = 0; }   // k 8..15 pad
            ebh = upack(h0, h1, h2, 0);
            ebl = upack(q0, q1, q2, 0);
        }

        // ---- stage m tile -> split-bf16 LDS (once per value) -------------
        #pragma unroll
        for (int i = 0; i < 9; ++i) {
            int f = tid + i * 256;
            if (f < M2) {
                int r = f / 67, c = f - r * 67;
                unsigned h, lo2; split_pack(mpre[i].x, mpre[i].y, h, lo2);
                *reinterpret_cast<unsigned*>(&mhs[r][2 * c]) = h;
                *reinterpret_cast<unsigned*>(&mls[r][2 * c]) = lo2;
            }
        }
        __syncthreads();   // barrier A: tile staged

        // ---- issue next tile's global loads (ride under MFMA) ------------
        if (t + GD < NT) { LOADM(t + GD); LOADE(t + GD); LOADSS(t + GD); }

        // ---- MFMA1 main: x = Wh.(mh+ml) (+bias), 18 MFMAs ----------------
        f32x16 acc  = {0,0,0,0,0,0,0,0,0,0,0,0,0,0,0,0};
        f32x16 acct = {0,0,0,0,0,0,0,0,0,0,0,0,0,0,0,0};
        #pragma unroll
        for (int ks = 0; ks < 9; ++ks) {
            bf16x8 bh = *reinterpret_cast<const bf16x8*>(&mhs[l31][ks * 16 + hi5 * 8]);
            bf16x8 bl = *reinterpret_cast<const bf16x8*>(&mls[l31][ks * 16 + hi5 * 8]);
            MF32(acc, wfh[ks], bh);
            MF32(acc, wfh[ks], bl);
        }
        MF32(acct, weh, ebh);
        MF32(acct, weh, ebl);

        // ---- mae = silu(x)*te -> RNE bf16 -> wave-private LDS slice ------
        #pragma unroll
        for (int q = 0; q < 4; ++q) {
            float mz[4];
            #pragma unroll
            for (int i = 0; i < 4; ++i) {
                float x  = acc[q * 4 + i];
                float sg = x / (1.f + __expf(-x));
                mz[i] = sg * acct[q * 4 + i];
            }
            const int cq = 32 * wv + 8 * q + 4 * hi5;
            *reinterpret_cast<uint2*>(&maeh[l31][cq]) =
                make_uint2(rne_pack(mz[0], mz[1]), rne_pack(mz[2], mz[3]));
        }

        // ---- MFMA3 main: own slice -> overlay [es][32wv..], 1 MFMA/nt ----
        #pragma unroll
        for (int nt = 0; nt < 2; ++nt) {
            f32x4 a3 = {0, 0, 0, 0};
            const int mr = nt * 16 + (l & 15);
            bf16x8 bh = *reinterpret_cast<const bf16x8*>(&maeh[mr][32 * wv + (l >> 4) * 8]);
            a3 = __builtin_amdgcn_mfma_f32_16x16x32_bf16(fwh, bh, a3, 0, 0, 0);
            const int g4 = l >> 4, es = nt * 16 + (l & 15);
            if (g4 == 0) {
                *reinterpret_cast<f32x4*>(&maeh[es][32 * wv]) = a3;
            } else if (g4 == 1) {
                *reinterpret_cast<float*>(&maeh[es][32 * wv + 8])  = a3[0];
                *reinterpret_cast<float*>(&maeh[es][32 * wv + 10]) = a3[1];
            }
        }

        // ---- TAIL group 4 (channels 128-133), one rotating wave ----------
        if (wv == ((blockIdx.x + it) & 3)) {
            const unsigned short* pf4 = FwF + ((size_t)4 * 64 + l) * 16;
            bf16x8 fw4h = *reinterpret_cast<const bf16x8*>(pf4);

            f32x16 acc4 = {0,0,0,0,0,0,0,0,0,0,0,0,0,0,0,0};
            #pragma unroll
            for (int ks = 0; ks < 9; ++ks) {   // A-frags from LDS (pipelined)
                bf16x8 a4h = *reinterpret_cast<const bf16x8*>(&wf4s[ks][l][0]);
                bf16x8 bh = *reinterpret_cast<const bf16x8*>(&mhs[l31][ks * 16 + hi5 * 8]);
                bf16x8 bl = *reinterpret_cast<const bf16x8*>(&mls[l31][ks * 16 + hi5 * 8]);
                MF32(acc4, a4h, bh);
                MF32(acc4, a4h, bl);
            }
            // te4 in fp32 VALU: reg i covers row (i&3)+8(i>>2)+4hi5
            float te4[4];
            #pragma unroll
            for (int i = 0; i < 4; ++i) {
                float dlo = er_s0 * we4[i][0] + er_s1 * we4[i][1] + er_s2 * we4[i][2]
                          + er_s3 * we4[i][3] + er_s4 * we4[i][4] + er_s5 * we4[i][5];
                float dhi = 0.f;
                if (i < 2)
                    dhi = er_s0 * we4[4 + i][0] + er_s1 * we4[4 + i][1] + er_s2 * we4[4 + i][2]
                        + er_s3 * we4[4 + i][3] + er_s4 * we4[4 + i][4] + er_s5 * we4[4 + i][5];
                te4[i] = hi5 ? dhi : dlo;
            }
            // mae4 (hi only; rows 0-5 live in q==0 regs)
            {
                float mz[4];
                #pragma unroll
                for (int i = 0; i < 4; ++i) {
                    float sg = acc4[i] / (1.f + __expf(-acc4[i]));
                    mz[i] = sg * te4[i];
                }
                const int cq = 128 + 4 * hi5;
                *reinterpret_cast<uint2*>(&maeh[l31][cq]) =
                    make_uint2(rne_pack(mz[0], mz[1]), rne_pack(mz[2], mz[3]));
                #pragma unroll
                for (int q = 1; q < 4; ++q)
                    *reinterpret_cast<uint2*>(&maeh[l31][128 + 8 * q + 4 * hi5]) = make_uint2(0, 0);
            }
            // tail MFMA3 -> overlay [es][128..]
            #pragma unroll
            for (int nt = 0; nt < 2; ++nt) {
                f32x4 a3 = {0, 0, 0, 0};
                const int mr = nt * 16 + (l & 15);
                bf16x8 bh = *reinterpret_cast<const bf16x8*>(&maeh[mr][128 + (l >> 4) * 8]);
                a3 = __builtin_amdgcn_mfma_f32_16x16x32_bf16(fw4h, bh, a3, 0, 0, 0);
                const int g4 = l >> 4, es = nt * 16 + (l & 15);
                if (g4 == 0) {
                    *reinterpret_cast<f32x4*>(&maeh[es][128]) = a3;
                } else if (g4 == 1) {
                    *reinterpret_cast<float*>(&maeh[es][128 + 8])  = a3[0];
                    *reinterpret_cast<float*>(&maeh[es][128 + 10]) = a3[1];
                }
            }
        }
        __syncthreads();   // barrier B: all overlays complete

        // ---- cross-group reduce + scale + store --------------------------
        if (tid < 192) {
            const int es = tid / 6, r = tid - es * 6;
            const int eo = e0 + es;
            if (eo < E) {
                float vsum = 0.f;
                #pragma unroll
                for (int w2 = 0; w2 < 5; ++w2)
                    vsum += *reinterpret_cast<const float*>(&maeh[es][32 * w2 + 2 * r]);
                out[(size_t)eo * NRBF + r] = vsum * ss_cur;
            }
        }
    }
#undef LOADM
#undef LOADE
#undef LOADSS
}

// ---------------------------------------------------------------------------
extern "C" void kernel_launch(void* const* d_in, const int* in_sizes, int n_in,
                              void* d_out, int out_size, void* d_ws, size_t ws_size,
                              hipStream_t stream)
{
    const float* m_ji    = (const float*)d_in[0];
    // d_in[1] nbr_list, d_in[2] angle_list: unused by the reference math
    const float* e_rbf   = (const float*)d_in[3];
    const float* a_sbf   = (const float*)d_in[4];
    const int*   kj_idx  = (const int*)  d_in[5];
    const float* W_m     = (const float*)d_in[6];
    const float* b_m     = (const float*)d_in[7];
    const float* W_e     = (const float*)d_in[8];
    const float* W_a     = (const float*)d_in[9];
    const float* final_w = (const float*)d_in[10];
    float* out = (float*)d_out;

    const int E  = in_sizes[0] / CAT;
    const int A  = in_sizes[5];
    const int NT = (E + TE - 1) / TE;

    // workspace layout
    char* ws = (char*)d_ws;
    float* sum_s = (float*)ws;
    size_t off = ((size_t)E * 4 + 255) & ~(size_t)255;
    unsigned short* WF  = (unsigned short*)(ws + off); off += (size_t)5 * 9 * 64 * 16 * 2;
    unsigned short* WeF = (unsigned short*)(ws + off); off += (size_t)5 * 64 * 16 * 2;
    unsigned short* FwF = (unsigned short*)(ws + off); off += (size_t)5 * 64 * 16 * 2;

    hipMemsetAsync(sum_s, 0, (size_t)E * sizeof(float), stream);

    const int prep_n = CHPAD * KPAD + CHPAD * 16 + 16 * CHPAD;
    prep_kernel<<<(prep_n + 255) / 256, 256, 0, stream>>>(
        W_m, b_m, W_e, final_w, WF, WeF, FwF);
    angle_kernel<<<(A + 255) / 256, 256, 0, stream>>>(a_sbf, kj_idx, W_a, sum_s, A);

    int grid = 2048; if (grid > NT) grid = NT;
    edge_kernel<<<grid, 256, 0, stream>>>(m_ji, e_rbf, W_e, WF, WeF, FwF,
                                          sum_s, out, E, NT);
}

// Round 18
// 131.309 us; speedup vs baseline: 1.5173x; 1.0786x over previous
//
#include <hip/hip_runtime.h>
#include <math.h>

#define CAT    134
#define NRBF   6
#define ADIM   42
#define NBIL   8
#define KPAD   144      // 9 k-steps of 16 (k=134 is the bias column)
#define CHPAD  160      // 5 groups x 32 channels
#define MSTR   152      // m LDS row stride (shorts): 304 B, 16B-aligned
#define TSTR   168      // mae row stride (shorts): 336 B, 16B-aligned
#define TE     32       // edges per tile
#define M2     (TE * 67)   // float2 count of one m tile (32*134/2)

typedef __bf16 bf16x8 __attribute__((ext_vector_type(8)));
typedef float  f32x16 __attribute__((ext_vector_type(16)));
typedef float  f32x4  __attribute__((ext_vector_type(4)));

__device__ __forceinline__ unsigned short f32_bf16_rne(float x) {
    union { float f; unsigned u; } v; v.f = x;
    unsigned u = v.u;
    u += 0x7FFFu + ((u >> 16) & 1u);
    return (unsigned short)(u >> 16);
}
__device__ __forceinline__ float bf16_f32(unsigned short h) {
    union { float f; unsigned u; } v; v.u = ((unsigned)h) << 16;
    return v.f;
}
// trunc split (used only for e_rbf, which keeps hi+lo precision)
__device__ __forceinline__ void split_pack(float a, float b, unsigned& ph, unsigned& pl) {
    unsigned ua = __float_as_uint(a), ub = __float_as_uint(b);
    ph = (ua >> 16) | (ub & 0xffff0000u);
    float ra = a - __uint_as_float(ua & 0xffff0000u);
    float rb = b - __uint_as_float(ub & 0xffff0000u);
    pl = (__float_as_uint(ra) >> 16) | (__float_as_uint(rb) & 0xffff0000u);
}
// RNE pack of two floats to a bf16 pair (m staging, mae)
__device__ __forceinline__ unsigned rne_pack(float a, float b) {
    return (unsigned)f32_bf16_rne(a) | ((unsigned)f32_bf16_rne(b) << 16);
}
__device__ __forceinline__ bf16x8 upack(unsigned a, unsigned b, unsigned c, unsigned d) {
    union { unsigned u[4]; bf16x8 v; } t;
    t.u[0] = a; t.u[1] = b; t.u[2] = c; t.u[3] = d;
    return t.v;
}

// ---------------------------------------------------------------------------
// prep: pack weights into FRAGMENT-MAJOR layout (hi+lo; kernel reads hi only)
// ---------------------------------------------------------------------------
__global__ __launch_bounds__(256) void prep_kernel(
    const float* __restrict__ Wm, const float* __restrict__ bm,
    const float* __restrict__ We, const float* __restrict__ fw,
    unsigned short* __restrict__ WF, unsigned short* __restrict__ WeF,
    unsigned short* __restrict__ FwF)
{
    int i = blockIdx.x * 256 + threadIdx.x;
    if (i < CHPAD * KPAD) {                                  // W_m (+bias col)
        int c = i / KPAD, k = i - c * KPAD;
        float v = 0.f;
        if (c < CAT) {
            if (k < CAT) v = Wm[c * CAT + k];
            else if (k == CAT) v = bm[c];
        }
        unsigned short h = f32_bf16_rne(v);
        unsigned short l = f32_bf16_rne(v - bf16_f32(h));
        int wv = c >> 5, l31 = c & 31, ks = k >> 4;
        int lane = ((k >> 3) & 1) * 32 + l31, j = k & 7;
        size_t idx = ((size_t)(wv * 9 + ks) * 64 + lane) * 16 + j;
        WF[idx] = h; WF[idx + 8] = l;
    } else if (i < CHPAD * KPAD + CHPAD * 16) {              // W_e (K -> 16)
        int j2 = i - CHPAD * KPAD; int c = j2 >> 4, r = j2 & 15;
        float v = (c < CAT && r < NRBF) ? We[c * NRBF + r] : 0.f;
        unsigned short h = f32_bf16_rne(v);
        unsigned short l = f32_bf16_rne(v - bf16_f32(h));
        int wv = c >> 5, l31 = c & 31;
        int lane = (r >> 3) * 32 + l31, j = r & 7;
        size_t idx = ((size_t)wv * 64 + lane) * 16 + j;
        WeF[idx] = h; WeF[idx + 8] = l;
    } else if (i < CHPAD * KPAD + CHPAD * 16 + 16 * CHPAD) { // final_w (16 rows)
        int j3 = i - CHPAD * KPAD - CHPAD * 16;
        int r = j3 / CHPAD, c = j3 - r * CHPAD;
        float v = (r < NRBF && c < CAT) ? fw[r * CAT + c] : 0.f;
        unsigned short h = f32_bf16_rne(v);
        unsigned short l = f32_bf16_rne(v - bf16_f32(h));
        int wv = c >> 5, kk = c & 31;
        int lane = (kk >> 3) * 16 + r, j = kk & 7;
        size_t idx = ((size_t)wv * 64 + lane) * 16 + j;
        FwF[idx] = h; FwF[idx + 8] = l;
    }
}

// ---------------------------------------------------------------------------
// angle: s_a = dot(a_sbf[a,:], colsum(W_a)), scatter-add into sum_s[kj]
// ---------------------------------------------------------------------------
__global__ __launch_bounds__(256) void angle_kernel(
    const float* __restrict__ a_sbf, const int* __restrict__ kj_idx,
    const float* __restrict__ W_a, float* __restrict__ sum_s, int A)
{
    __shared__ float wsum[ADIM];
    int tid = threadIdx.x;
    if (tid < ADIM) {
        float s = 0.f;
        #pragma unroll
        for (int b = 0; b < NBIL; ++b) s += W_a[b * ADIM + tid];
        wsum[tid] = s;
    }
    __syncthreads();

    int a = blockIdx.x * 256 + tid;
    if (a >= A) return;

    const float* row = a_sbf + (size_t)a * ADIM;
    float s = 0.f;
    #pragma unroll
    for (int d2 = 0; d2 < ADIM / 2; ++d2) {
        float2 v = *reinterpret_cast<const float2*>(row + d2 * 2);
        s += v.x * wsum[d2 * 2] + v.y * wsum[d2 * 2 + 1];
    }
    atomicAdd(&sum_s[kj_idx[a]], s);
}

// Zero-instruction opaque pin: hi-only weight set (44 VGPRs).
#define PIN_WEIGHTS()                                                          \
    asm volatile("" :                                                         \
        "+v"(wfh[0]), "+v"(wfh[1]), "+v"(wfh[2]), "+v"(wfh[3]), "+v"(wfh[4]), \
        "+v"(wfh[5]), "+v"(wfh[6]), "+v"(wfh[7]), "+v"(wfh[8]),               \
        "+v"(weh), "+v"(fwh))

#define MF32(AC, W, B) AC = __builtin_amdgcn_mfma_f32_32x32x16_bf16(W, B, AC, 0, 0, 0)

// ---------------------------------------------------------------------------
// edge: R17 structure (3 waves/EU pinned, validated) + PURE-BF16 MFMA1:
// m staged as RNE bf16 only (mls deleted) -> MFMA1 is 9 MFMAs, tail 9,
// staging conversion halves. e_rbf keeps hi+lo (1 extra MFMA). LDS 29.7 KB.
// absmax budget: W-lo drop gave 0.125; m-lo drop predicted ~0.25 < 0.475.
// ---------------------------------------------------------------------------
__global__ __launch_bounds__(256)
__attribute__((amdgpu_waves_per_eu(3, 3)))
void edge_kernel(
    const float* __restrict__ m_ji, const float* __restrict__ e_rbf,
    const float* __restrict__ We_raw,
    const unsigned short* __restrict__ WF, const unsigned short* __restrict__ WeF,
    const unsigned short* __restrict__ FwF,
    const float* __restrict__ sum_s, float* __restrict__ out, int E, int NT)
{
    __shared__ unsigned short mhs[TE][MSTR];    //  9728 B
    __shared__ unsigned short maeh[TE][TSTR];   // 10752 B (proj overlaid)
    __shared__ unsigned short wf4s[9][64][8];   //  9216 B  -> 29696 B total

    const int tid = threadIdx.x;
    const int l   = tid & 63;
    const int wv  = __builtin_amdgcn_readfirstlane(tid >> 6);  // 0..3
    const int l31 = l & 31;
    const int hi5 = l >> 5;
    const int GD  = gridDim.x;

    // ---- resident HI weight fragments for this wave's main group ---------
    bf16x8 wfh[9];
    #pragma unroll
    for (int ks = 0; ks < 9; ++ks)
        wfh[ks] = *reinterpret_cast<const bf16x8*>(WF + ((size_t)(wv * 9 + ks) * 64 + l) * 16);
    bf16x8 weh = *reinterpret_cast<const bf16x8*>(WeF + ((size_t)wv * 64 + l) * 16);
    bf16x8 fwh = *reinterpret_cast<const bf16x8*>(FwF + ((size_t)wv * 64 + l) * 16);
    PIN_WEIGHTS();

    // ---- stage tail group-4 HI A-fragments into LDS (once) ---------------
    {
        for (int f = tid; f < 9 * 64; f += 256) {   // 576 x 16B (hi half only)
            int ks = f / 64, ln = f - ks * 64;
            const uint4* src = reinterpret_cast<const uint4*>(
                WF + ((size_t)(4 * 9 + ks) * 64 + ln) * 16);
            *reinterpret_cast<uint4*>(&wf4s[ks][ln][0]) = src[0];
        }
    }

    // ---- wave-uniform W_e scalars for tail te (rows 128..133) -> SGPRs ---
    float we4[6][6];
    #pragma unroll
    for (int r0 = 0; r0 < 6; ++r0)
        #pragma unroll
        for (int r = 0; r < 6; ++r)
            we4[r0][r] = We_raw[(size_t)(128 + r0) * NRBF + r];

    // ---- one-time LDS init: m bias/pad cols 134..143 ---------------------
    if (tid < 160) {
        int r = tid / 5, j = tid - r * 5;
        *reinterpret_cast<unsigned*>(&mhs[r][134 + 2 * j]) = (j == 0) ? 0x00003F80u : 0u;
    }

    // ---- per-lane prefetch state -----------------------------------------
    float2 mpre[9];
    float2 er01, er23, er45;
    float  ssp;

#define LOADM(T)                                                              \
    do { int tt = (T);                                                        \
        const float2* mb = reinterpret_cast<const float2*>(m_ji + (size_t)tt * TE * CAT); \
        int nv2 = min(TE, E - tt * TE) * 67;                                  \
        _Pragma("unroll")                                                     \
        for (int i_ = 0; i_ < 9; ++i_) {                                      \
            int f_ = tid + i_ * 256;                                          \
            mpre[i_] = (f_ < nv2) ? mb[f_] : make_float2(0.f, 0.f);           \
        }                                                                     \
    } while (0)

#define LOADE(T)                                                              \
    do { int tt = (T);                                                        \
        er01 = make_float2(0.f, 0.f); er23 = er01; er45 = er01;               \
        int e_ = tt * TE + l31;                                               \
        if (e_ < E) {                                                         \
            const float* ep_ = e_rbf + (size_t)e_ * NRBF;                     \
            er01 = *reinterpret_cast<const float2*>(ep_);                     \
            er23 = *reinterpret_cast<const float2*>(ep_ + 2);                 \
            er45 = *reinterpret_cast<const float2*>(ep_ + 4);                 \
        }                                                                     \
    } while (0)

#define LOADSS(T)                                                             \
    do { int tt = (T);                                                        \
        ssp = 0.f;                                                            \
        if (tid < 192) {                                                      \
            int eo_ = tt * TE + tid / 6;                                      \
            if (eo_ < E) ssp = sum_s[eo_];                                    \
        }                                                                     \
    } while (0)

    // ---- prologue: prefetch tile t0 ---------------------------------------
    {
        int t0 = blockIdx.x;
        LOADM(t0); LOADE(t0); LOADSS(t0);
    }

    int it = 0;
    for (int t = blockIdx.x; t < NT; t += GD, ++it) {
        const int e0 = t * TE;
        PIN_WEIGHTS();

        // ---- latch this tile's er (tail te) + ss; build eb frags ---------
        float er_s0 = er01.x, er_s1 = er01.y, er_s2 = er23.x,
              er_s3 = er23.y, er_s4 = er45.x, er_s5 = er45.y;
        const float ss_cur = ssp;
        bf16x8 ebh, ebl;
        {
            unsigned h0, h1, h2, q0, q1, q2;
            split_pack(er01.x, er01.y, h0, q0);
            split_pack(er23.x, er23.y, h1, q1);
            split_pack(er45.x, er45.y, h2, q2);
            if (hi5) { h0 = h1 = h2 = q0 = q1 = q2 = 0; }   // k 8..15 pad
            ebh = upack(h0, h1, h2, 0);
            ebl = upack(q0, q1, q2, 0);
        }

        // ---- stage m tile -> RNE bf16 LDS (hi only) ----------------------
        #pragma unroll
        for (int i = 0; i < 9; ++i) {
            int f = tid + i * 256;
            if (f < M2) {
                int r = f / 67, c = f - r * 67;
                *reinterpret_cast<unsigned*>(&mhs[r][2 * c]) = rne_pack(mpre[i].x, mpre[i].y);
            }
        }
        __syncthreads();   // barrier A: tile staged

        // ---- issue next tile's global loads (ride under MFMA) ------------
        if (t + GD < NT) { LOADM(t + GD); LOADE(t + GD); LOADSS(t + GD); }

        // ---- MFMA1 main: x = Wh.mh (+bias), 9 MFMAs ----------------------
        f32x16 acc  = {0,0,0,0,0,0,0,0,0,0,0,0,0,0,0,0};
        f32x16 acct = {0,0,0,0,0,0,0,0,0,0,0,0,0,0,0,0};
        #pragma unroll
        for (int ks = 0; ks < 9; ++ks) {
            bf16x8 bh = *reinterpret_cast<const bf16x8*>(&mhs[l31][ks * 16 + hi5 * 8]);
            MF32(acc, wfh[ks], bh);
        }
        MF32(acct, weh, ebh);
        MF32(acct, weh, ebl);

        // ---- mae = silu(x)*te -> RNE bf16 -> wave-private LDS slice ------
        #pragma unroll
        for (int q = 0; q < 4; ++q) {
            float mz[4];
            #pragma unroll
            for (int i = 0; i < 4; ++i) {
                float x  = acc[q * 4 + i];
                float sg = x / (1.f + __expf(-x));
                mz[i] = sg * acct[q * 4 + i];
            }
            const int cq = 32 * wv + 8 * q + 4 * hi5;
            *reinterpret_cast<uint2*>(&maeh[l31][cq]) =
                make_uint2(rne_pack(mz[0], mz[1]), rne_pack(mz[2], mz[3]));
        }

        // ---- MFMA3 main: own slice -> overlay [es][32wv..], 1 MFMA/nt ----
        #pragma unroll
        for (int nt = 0; nt < 2; ++nt) {
            f32x4 a3 = {0, 0, 0, 0};
            const int mr = nt * 16 + (l & 15);
            bf16x8 bh = *reinterpret_cast<const bf16x8*>(&maeh[mr][32 * wv + (l >> 4) * 8]);
            a3 = __builtin_amdgcn_mfma_f32_16x16x32_bf16(fwh, bh, a3, 0, 0, 0);
            const int g4 = l >> 4, es = nt * 16 + (l & 15);
            if (g4 == 0) {
                *reinterpret_cast<f32x4*>(&maeh[es][32 * wv]) = a3;
            } else if (g4 == 1) {
                *reinterpret_cast<float*>(&maeh[es][32 * wv + 8])  = a3[0];
                *reinterpret_cast<float*>(&maeh[es][32 * wv + 10]) = a3[1];
            }
        }

        // ---- TAIL group 4 (channels 128-133), one rotating wave ----------
        if (wv == ((blockIdx.x + it) & 3)) {
            const unsigned short* pf4 = FwF + ((size_t)4 * 64 + l) * 16;
            bf16x8 fw4h = *reinterpret_cast<const bf16x8*>(pf4);

            f32x16 acc4 = {0,0,0,0,0,0,0,0,0,0,0,0,0,0,0,0};
            #pragma unroll
            for (int ks = 0; ks < 9; ++ks) {   // A-frags from LDS (pipelined)
                bf16x8 a4h = *reinterpret_cast<const bf16x8*>(&wf4s[ks][l][0]);
                bf16x8 bh = *reinterpret_cast<const bf16x8*>(&mhs[l31][ks * 16 + hi5 * 8]);
                MF32(acc4, a4h, bh);
            }
            // te4 in fp32 VALU: reg i covers row (i&3)+8(i>>2)+4hi5
            float te4[4];
            #pragma unroll
            for (int i = 0; i < 4; ++i) {
                float dlo = er_s0 * we4[i][0] + er_s1 * we4[i][1] + er_s2 * we4[i][2]
                          + er_s3 * we4[i][3] + er_s4 * we4[i][4] + er_s5 * we4[i][5];
                float dhi = 0.f;
                if (i < 2)
                    dhi = er_s0 * we4[4 + i][0] + er_s1 * we4[4 + i][1] + er_s2 * we4[4 + i][2]
                        + er_s3 * we4[4 + i][3] + er_s4 * we4[4 + i][4] + er_s5 * we4[4 + i][5];
                te4[i] = hi5 ? dhi : dlo;
            }
            // mae4 (hi only; rows 0-5 live in q==0 regs)
            {
                float mz[4];
                #pragma unroll
                for (int i = 0; i < 4; ++i) {
                    float sg = acc4[i] / (1.f + __expf(-acc4[i]));
                    mz[i] = sg * te4[i];
                }
                const int cq = 128 + 4 * hi5;
                *reinterpret_cast<uint2*>(&maeh[l31][cq]) =
                    make_uint2(rne_pack(mz[0], mz[1]), rne_pack(mz[2], mz[3]));
                #pragma unroll
                for (int q = 1; q < 4; ++q)
                    *reinterpret_cast<uint2*>(&maeh[l31][128 + 8 * q + 4 * hi5]) = make_uint2(0, 0);
            }
            // tail MFMA3 -> overlay [es][128..]
            #pragma unroll
            for (int nt = 0; nt < 2; ++nt) {
                f32x4 a3 = {0, 0, 0, 0};
                const int mr = nt * 16 + (l & 15);
                bf16x8 bh = *reinterpret_cast<const bf16x8*>(&maeh[mr][128 + (l >> 4) * 8]);
                a3 = __builtin_amdgcn_mfma_f32_16x16x32_bf16(fw4h, bh, a3, 0, 0, 0);
                const int g4 = l >> 4, es = nt * 16 + (l & 15);
                if (g4 == 0) {
                    *reinterpret_cast<f32x4*>(&maeh[es][128]) = a3;
                } else if (g4 == 1) {
                    *reinterpret_cast<float*>(&maeh[es][128 + 8])  = a3[0];
                    *reinterpret_cast<float*>(&maeh[es][128 + 10]) = a3[1];
                }
            }
        }
        __syncthreads();   // barrier B: all overlays complete

        // ---- cross-group reduce + scale + store --------------------------
        if (tid < 192) {
            const int es = tid / 6, r = tid - es * 6;
            const int eo = e0 + es;
            if (eo < E) {
                float vsum = 0.f;
                #pragma unroll
                for (int w2 = 0; w2 < 5; ++w2)
                    vsum += *reinterpret_cast<const float*>(&maeh[es][32 * w2 + 2 * r]);
                out[(size_t)eo * NRBF + r] = vsum * ss_cur;
            }
        }
    }
#undef LOADM
#undef LOADE
#undef LOADSS
}

// ---------------------------------------------------------------------------
extern "C" void kernel_launch(void* const* d_in, const int* in_sizes, int n_in,
                              void* d_out, int out_size, void* d_ws, size_t ws_size,
                              hipStream_t stream)
{
    const float* m_ji    = (const float*)d_in[0];
    // d_in[1] nbr_list, d_in[2] angle_list: unused by the reference math
    const float* e_rbf   = (const float*)d_in[3];
    const float* a_sbf   = (const float*)d_in[4];
    const int*   kj_idx  = (const int*)  d_in[5];
    const float* W_m     = (const float*)d_in[6];
    const float* b_m     = (const float*)d_in[7];
    const float* W_e     = (const float*)d_in[8];
    const float* W_a     = (const float*)d_in[9];
    const float* final_w = (const float*)d_in[10];
    float* out = (float*)d_out;

    const int E  = in_sizes[0] / CAT;
    const int A  = in_sizes[5];
    const int NT = (E + TE - 1) / TE;

    // workspace layout
    char* ws = (char*)d_ws;
    float* sum_s = (float*)ws;
    size_t off = ((size_t)E * 4 + 255) & ~(size_t)255;
    unsigned short* WF  = (unsigned short*)(ws + off); off += (size_t)5 * 9 * 64 * 16 * 2;
    unsigned short* WeF = (unsigned short*)(ws + off); off += (size_t)5 * 64 * 16 * 2;
    unsigned short* FwF = (unsigned short*)(ws + off); off += (size_t)5 * 64 * 16 * 2;

    hipMemsetAsync(sum_s, 0, (size_t)E * sizeof(float), stream);

    const int prep_n = CHPAD * KPAD + CHPAD * 16 + 16 * CHPAD;
    prep_kernel<<<(prep_n + 255) / 256, 256, 0, stream>>>(
        W_m, b_m, W_e, final_w, WF, WeF, FwF);
    angle_kernel<<<(A + 255) / 256, 256, 0, stream>>>(a_sbf, kj_idx, W_a, sum_s, A);

    int grid = 2048; if (grid > NT) grid = NT;
    edge_kernel<<<grid, 256, 0, stream>>>(m_ji, e_rbf, W_e, WF, WeF, FwF,
                                          sum_s, out, E, NT);
}

// Round 19
// 125.282 us; speedup vs baseline: 1.5903x; 1.0481x over previous
//
#include <hip/hip_runtime.h>
#include <math.h>

#define CAT    134
#define NRBF   6
#define ADIM   42
#define NBIL   8
#define KPAD   144      // 9 k-steps of 16 (k=134 is the bias column)
#define CHPAD  160      // 5 groups x 32 channels
#define MSTR   152      // m LDS row stride (shorts): 304 B, 16B-aligned
#define TSTR   168      // mae row stride (shorts): 336 B, 16B-aligned
#define TE     32       // edges per tile
#define M2     (TE * 67)   // float2 count of one m tile (32*134/2)

typedef __bf16 bf16x8 __attribute__((ext_vector_type(8)));
typedef float  f32x16 __attribute__((ext_vector_type(16)));
typedef float  f32x4  __attribute__((ext_vector_type(4)));

__device__ __forceinline__ unsigned short f32_bf16_rne(float x) {
    union { float f; unsigned u; } v; v.f = x;
    unsigned u = v.u;
    u += 0x7FFFu + ((u >> 16) & 1u);
    return (unsigned short)(u >> 16);
}
__device__ __forceinline__ float bf16_f32(unsigned short h) {
    union { float f; unsigned u; } v; v.u = ((unsigned)h) << 16;
    return v.f;
}
// trunc split (used only for e_rbf, which keeps hi+lo precision)
__device__ __forceinline__ void split_pack(float a, float b, unsigned& ph, unsigned& pl) {
    unsigned ua = __float_as_uint(a), ub = __float_as_uint(b);
    ph = (ua >> 16) | (ub & 0xffff0000u);
    float ra = a - __uint_as_float(ua & 0xffff0000u);
    float rb = b - __uint_as_float(ub & 0xffff0000u);
    pl = (__float_as_uint(ra) >> 16) | (__float_as_uint(rb) & 0xffff0000u);
}
// RNE pack of two floats to a bf16 pair (m staging, mae)
__device__ __forceinline__ unsigned rne_pack(float a, float b) {
    return (unsigned)f32_bf16_rne(a) | ((unsigned)f32_bf16_rne(b) << 16);
}
__device__ __forceinline__ bf16x8 upack(unsigned a, unsigned b, unsigned c, unsigned d) {
    union { unsigned u[4]; bf16x8 v; } t;
    t.u[0] = a; t.u[1] = b; t.u[2] = c; t.u[3] = d;
    return t.v;
}
// fast silu: x * rcp(1+exp(-x)) -- v_rcp_f32 is ~1ulp; avoids the ~10-instr
// IEEE fp32 divide sequence (div_scale/div_fmas/div_fixup) per element.
__device__ __forceinline__ float fast_silu(float x) {
    return x * __builtin_amdgcn_rcpf(1.f + __expf(-x));
}

// ---------------------------------------------------------------------------
// prep: pack weights into FRAGMENT-MAJOR layout (hi+lo; kernel reads hi only)
// ---------------------------------------------------------------------------
__global__ __launch_bounds__(256) void prep_kernel(
    const float* __restrict__ Wm, const float* __restrict__ bm,
    const float* __restrict__ We, const float* __restrict__ fw,
    unsigned short* __restrict__ WF, unsigned short* __restrict__ WeF,
    unsigned short* __restrict__ FwF)
{
    int i = blockIdx.x * 256 + threadIdx.x;
    if (i < CHPAD * KPAD) {                                  // W_m (+bias col)
        int c = i / KPAD, k = i - c * KPAD;
        float v = 0.f;
        if (c < CAT) {
            if (k < CAT) v = Wm[c * CAT + k];
            else if (k == CAT) v = bm[c];
        }
        unsigned short h = f32_bf16_rne(v);
        unsigned short l = f32_bf16_rne(v - bf16_f32(h));
        int wv = c >> 5, l31 = c & 31, ks = k >> 4;
        int lane = ((k >> 3) & 1) * 32 + l31, j = k & 7;
        size_t idx = ((size_t)(wv * 9 + ks) * 64 + lane) * 16 + j;
        WF[idx] = h; WF[idx + 8] = l;
    } else if (i < CHPAD * KPAD + CHPAD * 16) {              // W_e (K -> 16)
        int j2 = i - CHPAD * KPAD; int c = j2 >> 4, r = j2 & 15;
        float v = (c < CAT && r < NRBF) ? We[c * NRBF + r] : 0.f;
        unsigned short h = f32_bf16_rne(v);
        unsigned short l = f32_bf16_rne(v - bf16_f32(h));
        int wv = c >> 5, l31 = c & 31;
        int lane = (r >> 3) * 32 + l31, j = r & 7;
        size_t idx = ((size_t)wv * 64 + lane) * 16 + j;
        WeF[idx] = h; WeF[idx + 8] = l;
    } else if (i < CHPAD * KPAD + CHPAD * 16 + 16 * CHPAD) { // final_w (16 rows)
        int j3 = i - CHPAD * KPAD - CHPAD * 16;
        int r = j3 / CHPAD, c = j3 - r * CHPAD;
        float v = (r < NRBF && c < CAT) ? fw[r * CAT + c] : 0.f;
        unsigned short h = f32_bf16_rne(v);
        unsigned short l = f32_bf16_rne(v - bf16_f32(h));
        int wv = c >> 5, kk = c & 31;
        int lane = (kk >> 3) * 16 + r, j = kk & 7;
        size_t idx = ((size_t)wv * 64 + lane) * 16 + j;
        FwF[idx] = h; FwF[idx + 8] = l;
    }
}

// ---------------------------------------------------------------------------
// angle: s_a = dot(a_sbf[a,:], colsum(W_a)), scatter-add into sum_s[kj]
// ---------------------------------------------------------------------------
__global__ __launch_bounds__(256) void angle_kernel(
    const float* __restrict__ a_sbf, const int* __restrict__ kj_idx,
    const float* __restrict__ W_a, float* __restrict__ sum_s, int A)
{
    __shared__ float wsum[ADIM];
    int tid = threadIdx.x;
    if (tid < ADIM) {
        float s = 0.f;
        #pragma unroll
        for (int b = 0; b < NBIL; ++b) s += W_a[b * ADIM + tid];
        wsum[tid] = s;
    }
    __syncthreads();

    int a = blockIdx.x * 256 + tid;
    if (a >= A) return;

    const float* row = a_sbf + (size_t)a * ADIM;
    float s = 0.f;
    #pragma unroll
    for (int d2 = 0; d2 < ADIM / 2; ++d2) {
        float2 v = *reinterpret_cast<const float2*>(row + d2 * 2);
        s += v.x * wsum[d2 * 2] + v.y * wsum[d2 * 2 + 1];
    }
    atomicAdd(&sum_s[kj_idx[a]], s);
}

// Zero-instruction opaque pin: hi-only weight set (44 VGPRs).
#define PIN_WEIGHTS()                                                          \
    asm volatile("" :                                                         \
        "+v"(wfh[0]), "+v"(wfh[1]), "+v"(wfh[2]), "+v"(wfh[3]), "+v"(wfh[4]), \
        "+v"(wfh[5]), "+v"(wfh[6]), "+v"(wfh[7]), "+v"(wfh[8]),               \
        "+v"(weh), "+v"(fwh))

#define MF32(AC, W, B) AC = __builtin_amdgcn_mfma_f32_32x32x16_bf16(W, B, AC, 0, 0, 0)

// ---------------------------------------------------------------------------
// edge: R18 structure (pure-bf16 MFMA1, 3 waves/EU pinned, LDS 29.7 KB) with
// fast_silu (v_rcp instead of the IEEE fp32 divide sequence) -- the divide
// was ~160 VALU instrs/thread/tile, the largest VALU block in the loop.
// ---------------------------------------------------------------------------
__global__ __launch_bounds__(256)
__attribute__((amdgpu_waves_per_eu(3, 3)))
void edge_kernel(
    const float* __restrict__ m_ji, const float* __restrict__ e_rbf,
    const float* __restrict__ We_raw,
    const unsigned short* __restrict__ WF, const unsigned short* __restrict__ WeF,
    const unsigned short* __restrict__ FwF,
    const float* __restrict__ sum_s, float* __restrict__ out, int E, int NT)
{
    __shared__ unsigned short mhs[TE][MSTR];    //  9728 B
    __shared__ unsigned short maeh[TE][TSTR];   // 10752 B (proj overlaid)
    __shared__ unsigned short wf4s[9][64][8];   //  9216 B  -> 29696 B total

    const int tid = threadIdx.x;
    const int l   = tid & 63;
    const int wv  = __builtin_amdgcn_readfirstlane(tid >> 6);  // 0..3
    const int l31 = l & 31;
    const int hi5 = l >> 5;
    const int GD  = gridDim.x;

    // ---- resident HI weight fragments for this wave's main group ---------
    bf16x8 wfh[9];
    #pragma unroll
    for (int ks = 0; ks < 9; ++ks)
        wfh[ks] = *reinterpret_cast<const bf16x8*>(WF + ((size_t)(wv * 9 + ks) * 64 + l) * 16);
    bf16x8 weh = *reinterpret_cast<const bf16x8*>(WeF + ((size_t)wv * 64 + l) * 16);
    bf16x8 fwh = *reinterpret_cast<const bf16x8*>(FwF + ((size_t)wv * 64 + l) * 16);
    PIN_WEIGHTS();

    // ---- stage tail group-4 HI A-fragments into LDS (once) ---------------
    {
        for (int f = tid; f < 9 * 64; f += 256) {   // 576 x 16B (hi half only)
            int ks = f / 64, ln = f - ks * 64;
            const uint4* src = reinterpret_cast<const uint4*>(
                WF + ((size_t)(4 * 9 + ks) * 64 + ln) * 16);
            *reinterpret_cast<uint4*>(&wf4s[ks][ln][0]) = src[0];
        }
    }

    // ---- wave-uniform W_e scalars for tail te (rows 128..133) -> SGPRs ---
    float we4[6][6];
    #pragma unroll
    for (int r0 = 0; r0 < 6; ++r0)
        #pragma unroll
        for (int r = 0; r < 6; ++r)
            we4[r0][r] = We_raw[(size_t)(128 + r0) * NRBF + r];

    // ---- one-time LDS init: m bias/pad cols 134..143 ---------------------
    if (tid < 160) {
        int r = tid / 5, j = tid - r * 5;
        *reinterpret_cast<unsigned*>(&mhs[r][134 + 2 * j]) = (j == 0) ? 0x00003F80u : 0u;
    }

    // ---- per-lane prefetch state -----------------------------------------
    float2 mpre[9];
    float2 er01, er23, er45;
    float  ssp;

#define LOADM(T)                                                              \
    do { int tt = (T);                                                        \
        const float2* mb = reinterpret_cast<const float2*>(m_ji + (size_t)tt * TE * CAT); \
        int nv2 = min(TE, E - tt * TE) * 67;                                  \
        _Pragma("unroll")                                                     \
        for (int i_ = 0; i_ < 9; ++i_) {                                      \
            int f_ = tid + i_ * 256;                                          \
            mpre[i_] = (f_ < nv2) ? mb[f_] : make_float2(0.f, 0.f);           \
        }                                                                     \
    } while (0)

#define LOADE(T)                                                              \
    do { int tt = (T);                                                        \
        er01 = make_float2(0.f, 0.f); er23 = er01; er45 = er01;               \
        int e_ = tt * TE + l31;                                               \
        if (e_ < E) {                                                         \
            const float* ep_ = e_rbf + (size_t)e_ * NRBF;                     \
            er01 = *reinterpret_cast<const float2*>(ep_);                     \
            er23 = *reinterpret_cast<const float2*>(ep_ + 2);                 \
            er45 = *reinterpret_cast<const float2*>(ep_ + 4);                 \
        }                                                                     \
    } while (0)

#define LOADSS(T)                                                             \
    do { int tt = (T);                                                        \
        ssp = 0.f;                                                            \
        if (tid < 192) {                                                      \
            int eo_ = tt * TE + tid / 6;                                      \
            if (eo_ < E) ssp = sum_s[eo_];                                    \
        }                                                                     \
    } while (0)

    // ---- prologue: prefetch tile t0 ---------------------------------------
    {
        int t0 = blockIdx.x;
        LOADM(t0); LOADE(t0); LOADSS(t0);
    }

    int it = 0;
    for (int t = blockIdx.x; t < NT; t += GD, ++it) {
        const int e0 = t * TE;
        PIN_WEIGHTS();

        // ---- latch this tile's er (tail te) + ss; build eb frags ---------
        float er_s0 = er01.x, er_s1 = er01.y, er_s2 = er23.x,
              er_s3 = er23.y, er_s4 = er45.x, er_s5 = er45.y;
        const float ss_cur = ssp;
        bf16x8 ebh, ebl;
        {
            unsigned h0, h1, h2, q0, q1, q2;
            split_pack(er01.x, er01.y, h0, q0);
            split_pack(er23.x, er23.y, h1, q1);
            split_pack(er45.x, er45.y, h2, q2);
            if (hi5) { h0 = h1 = h2 = q0 = q1 = q2 = 0; }   // k 8..15 pad
            ebh = upack(h0, h1, h2, 0);
            ebl = upack(q0, q1, q2, 0);
        }

        // ---- stage m tile -> RNE bf16 LDS (hi only) ----------------------
        #pragma unroll
        for (int i = 0; i < 9; ++i) {
            int f = tid + i * 256;
            if (f < M2) {
                int r = f / 67, c = f - r * 67;
                *reinterpret_cast<unsigned*>(&mhs[r][2 * c]) = rne_pack(mpre[i].x, mpre[i].y);
            }
        }
        __syncthreads();   // barrier A: tile staged

        // ---- issue next tile's global loads (ride under MFMA) ------------
        if (t + GD < NT) { LOADM(t + GD); LOADE(t + GD); LOADSS(t + GD); }

        // ---- MFMA1 main: x = Wh.mh (+bias), 9 MFMAs ----------------------
        f32x16 acc  = {0,0,0,0,0,0,0,0,0,0,0,0,0,0,0,0};
        f32x16 acct = {0,0,0,0,0,0,0,0,0,0,0,0,0,0,0,0};
        #pragma unroll
        for (int ks = 0; ks < 9; ++ks) {
            bf16x8 bh = *reinterpret_cast<const bf16x8*>(&mhs[l31][ks * 16 + hi5 * 8]);
            MF32(acc, wfh[ks], bh);
        }
        MF32(acct, weh, ebh);
        MF32(acct, weh, ebl);

        // ---- mae = silu(x)*te -> RNE bf16 -> wave-private LDS slice ------
        #pragma unroll
        for (int q = 0; q < 4; ++q) {
            float mz[4];
            #pragma unroll
            for (int i = 0; i < 4; ++i)
                mz[i] = fast_silu(acc[q * 4 + i]) * acct[q * 4 + i];
            const int cq = 32 * wv + 8 * q + 4 * hi5;
            *reinterpret_cast<uint2*>(&maeh[l31][cq]) =
                make_uint2(rne_pack(mz[0], mz[1]), rne_pack(mz[2], mz[3]));
        }

        // ---- MFMA3 main: own slice -> overlay [es][32wv..], 1 MFMA/nt ----
        #pragma unroll
        for (int nt = 0; nt < 2; ++nt) {
            f32x4 a3 = {0, 0, 0, 0};
            const int mr = nt * 16 + (l & 15);
            bf16x8 bh = *reinterpret_cast<const bf16x8*>(&maeh[mr][32 * wv + (l >> 4) * 8]);
            a3 = __builtin_amdgcn_mfma_f32_16x16x32_bf16(fwh, bh, a3, 0, 0, 0);
            const int g4 = l >> 4, es = nt * 16 + (l & 15);
            if (g4 == 0) {
                *reinterpret_cast<f32x4*>(&maeh[es][32 * wv]) = a3;
            } else if (g4 == 1) {
                *reinterpret_cast<float*>(&maeh[es][32 * wv + 8])  = a3[0];
                *reinterpret_cast<float*>(&maeh[es][32 * wv + 10]) = a3[1];
            }
        }

        // ---- TAIL group 4 (channels 128-133), one rotating wave ----------
        if (wv == ((blockIdx.x + it) & 3)) {
            const unsigned short* pf4 = FwF + ((size_t)4 * 64 + l) * 16;
            bf16x8 fw4h = *reinterpret_cast<const bf16x8*>(pf4);

            f32x16 acc4 = {0,0,0,0,0,0,0,0,0,0,0,0,0,0,0,0};
            #pragma unroll
            for (int ks = 0; ks < 9; ++ks) {   // A-frags from LDS (pipelined)
                bf16x8 a4h = *reinterpret_cast<const bf16x8*>(&wf4s[ks][l][0]);
                bf16x8 bh = *reinterpret_cast<const bf16x8*>(&mhs[l31][ks * 16 + hi5 * 8]);
                MF32(acc4, a4h, bh);
            }
            // te4 in fp32 VALU: reg i covers row (i&3)+8(i>>2)+4hi5
            float te4[4];
            #pragma unroll
            for (int i = 0; i < 4; ++i) {
                float dlo = er_s0 * we4[i][0] + er_s1 * we4[i][1] + er_s2 * we4[i][2]
                          + er_s3 * we4[i][3] + er_s4 * we4[i][4] + er_s5 * we4[i][5];
                float dhi = 0.f;
                if (i < 2)
                    dhi = er_s0 * we4[4 + i][0] + er_s1 * we4[4 + i][1] + er_s2 * we4[4 + i][2]
                        + er_s3 * we4[4 + i][3] + er_s4 * we4[4 + i][4] + er_s5 * we4[4 + i][5];
                te4[i] = hi5 ? dhi : dlo;
            }
            // mae4 (hi only; rows 0-5 live in q==0 regs)
            {
                float mz[4];
                #pragma unroll
                for (int i = 0; i < 4; ++i)
                    mz[i] = fast_silu(acc4[i]) * te4[i];
                const int cq = 128 + 4 * hi5;
                *reinterpret_cast<uint2*>(&maeh[l31][cq]) =
                    make_uint2(rne_pack(mz[0], mz[1]), rne_pack(mz[2], mz[3]));
                #pragma unroll
                for (int q = 1; q < 4; ++q)
                    *reinterpret_cast<uint2*>(&maeh[l31][128 + 8 * q + 4 * hi5]) = make_uint2(0, 0);
            }
            // tail MFMA3 -> overlay [es][128..]
            #pragma unroll
            for (int nt = 0; nt < 2; ++nt) {
                f32x4 a3 = {0, 0, 0, 0};
                const int mr = nt * 16 + (l & 15);
                bf16x8 bh = *reinterpret_cast<const bf16x8*>(&maeh[mr][128 + (l >> 4) * 8]);
                a3 = __builtin_amdgcn_mfma_f32_16x16x32_bf16(fw4h, bh, a3, 0, 0, 0);
                const int g4 = l >> 4, es = nt * 16 + (l & 15);
                if (g4 == 0) {
                    *reinterpret_cast<f32x4*>(&maeh[es][128]) = a3;
                } else if (g4 == 1) {
                    *reinterpret_cast<float*>(&maeh[es][128 + 8])  = a3[0];
                    *reinterpret_cast<float*>(&maeh[es][128 + 10]) = a3[1];
                }
            }
        }
        __syncthreads();   // barrier B: all overlays complete

        // ---- cross-group reduce + scale + store --------------------------
        if (tid < 192) {
            const int es = tid / 6, r = tid - es * 6;
            const int eo = e0 + es;
            if (eo < E) {
                float vsum = 0.f;
                #pragma unroll
                for (int w2 = 0; w2 < 5; ++w2)
                    vsum += *reinterpret_cast<const float*>(&maeh[es][32 * w2 + 2 * r]);
                out[(size_t)eo * NRBF + r] = vsum * ss_cur;
            }
        }
    }
#undef LOADM
#undef LOADE
#undef LOADSS
}

// ---------------------------------------------------------------------------
extern "C" void kernel_launch(void* const* d_in, const int* in_sizes, int n_in,
                              void* d_out, int out_size, void* d_ws, size_t ws_size,
                              hipStream_t stream)
{
    const float* m_ji    = (const float*)d_in[0];
    // d_in[1] nbr_list, d_in[2] angle_list: unused by the reference math
    const float* e_rbf   = (const float*)d_in[3];
    const float* a_sbf   = (const float*)d_in[4];
    const int*   kj_idx  = (const int*)  d_in[5];
    const float* W_m     = (const float*)d_in[6];
    const float* b_m     = (const float*)d_in[7];
    const float* W_e     = (const float*)d_in[8];
    const float* W_a     = (const float*)d_in[9];
    const float* final_w = (const float*)d_in[10];
    float* out = (float*)d_out;

    const int E  = in_sizes[0] / CAT;
    const int A  = in_sizes[5];
    const int NT = (E + TE - 1) / TE;

    // workspace layout
    char* ws = (char*)d_ws;
    float* sum_s = (float*)ws;
    size_t off = ((size_t)E * 4 + 255) & ~(size_t)255;
    unsigned short* WF  = (unsigned short*)(ws + off); off += (size_t)5 * 9 * 64 * 16 * 2;
    unsigned short* WeF = (unsigned short*)(ws + off); off += (size_t)5 * 64 * 16 * 2;
    unsigned short* FwF = (unsigned short*)(ws + off); off += (size_t)5 * 64 * 16 * 2;

    hipMemsetAsync(sum_s, 0, (size_t)E * sizeof(float), stream);

    const int prep_n = CHPAD * KPAD + CHPAD * 16 + 16 * CHPAD;
    prep_kernel<<<(prep_n + 255) / 256, 256, 0, stream>>>(
        W_m, b_m, W_e, final_w, WF, WeF, FwF);
    angle_kernel<<<(A + 255) / 256, 256, 0, stream>>>(a_sbf, kj_idx, W_a, sum_s, A);

    int grid = 2048; if (grid > NT) grid = NT;
    edge_kernel<<<grid, 256, 0, stream>>>(m_ji, e_rbf, W_e, WF, WeF, FwF,
                                          sum_s, out, E, NT);
}

// Round 20
// 114.016 us; speedup vs baseline: 1.7475x; 1.0988x over previous
//
#include <hip/hip_runtime.h>
#include <math.h>

#define CAT    134
#define NRBF   6
#define ADIM   42
#define NBIL   8
#define KPAD   144      // 9 k-steps of 16 (k=134 is the bias column)
#define CHPAD  160      // 5 groups x 32 channels
#define MSTR   152      // m LDS row stride (shorts): 304 B, 16B-aligned
#define TSTR   168      // mae row stride (shorts): 336 B, 16B-aligned
#define TE     32       // edges per tile
#define M2     (TE * 67)   // float2 count of one m tile (32*134/2)

typedef __bf16 bf16x8 __attribute__((ext_vector_type(8)));
typedef float  f32x16 __attribute__((ext_vector_type(16)));
typedef float  f32x4  __attribute__((ext_vector_type(4)));

__device__ __forceinline__ unsigned short f32_bf16_rne(float x) {
    union { float f; unsigned u; } v; v.f = x;
    unsigned u = v.u;
    u += 0x7FFFu + ((u >> 16) & 1u);
    return (unsigned short)(u >> 16);
}
__device__ __forceinline__ float bf16_f32(unsigned short h) {
    union { float f; unsigned u; } v; v.u = ((unsigned)h) << 16;
    return v.f;
}
// RNE pack of two floats to a bf16 pair
__device__ __forceinline__ unsigned rne_pack(float a, float b) {
    return (unsigned)f32_bf16_rne(a) | ((unsigned)f32_bf16_rne(b) << 16);
}
__device__ __forceinline__ bf16x8 upack(unsigned a, unsigned b, unsigned c, unsigned d) {
    union { unsigned u[4]; bf16x8 v; } t;
    t.u[0] = a; t.u[1] = b; t.u[2] = c; t.u[3] = d;
    return t.v;
}
// fast silu: x * rcp(1+exp(-x)) -- avoids the IEEE fp32 divide sequence.
__device__ __forceinline__ float fast_silu(float x) {
    return x * __builtin_amdgcn_rcpf(1.f + __expf(-x));
}

// ---------------------------------------------------------------------------
// prep: pack weights into FRAGMENT-MAJOR layout (hi+lo; kernel reads hi only)
// + zero sum_s (replaces the hipMemsetAsync graph node)
// ---------------------------------------------------------------------------
__global__ __launch_bounds__(256) void prep_kernel(
    const float* __restrict__ Wm, const float* __restrict__ bm,
    const float* __restrict__ We, const float* __restrict__ fw,
    unsigned short* __restrict__ WF, unsigned short* __restrict__ WeF,
    unsigned short* __restrict__ FwF, float* __restrict__ sum_s, int E)
{
    int i = blockIdx.x * 256 + threadIdx.x;
    if (i < E) sum_s[i] = 0.f;
    if (i < CHPAD * KPAD) {                                  // W_m (+bias col)
        int c = i / KPAD, k = i - c * KPAD;
        float v = 0.f;
        if (c < CAT) {
            if (k < CAT) v = Wm[c * CAT + k];
            else if (k == CAT) v = bm[c];
        }
        unsigned short h = f32_bf16_rne(v);
        unsigned short l = f32_bf16_rne(v - bf16_f32(h));
        int wv = c >> 5, l31 = c & 31, ks = k >> 4;
        int lane = ((k >> 3) & 1) * 32 + l31, j = k & 7;
        size_t idx = ((size_t)(wv * 9 + ks) * 64 + lane) * 16 + j;
        WF[idx] = h; WF[idx + 8] = l;
    } else if (i < CHPAD * KPAD + CHPAD * 16) {              // W_e (K -> 16)
        int j2 = i - CHPAD * KPAD; int c = j2 >> 4, r = j2 & 15;
        float v = (c < CAT && r < NRBF) ? We[c * NRBF + r] : 0.f;
        unsigned short h = f32_bf16_rne(v);
        unsigned short l = f32_bf16_rne(v - bf16_f32(h));
        int wv = c >> 5, l31 = c & 31;
        int lane = (r >> 3) * 32 + l31, j = r & 7;
        size_t idx = ((size_t)wv * 64 + lane) * 16 + j;
        WeF[idx] = h; WeF[idx + 8] = l;
    } else if (i < CHPAD * KPAD + CHPAD * 16 + 16 * CHPAD) { // final_w (16 rows)
        int j3 = i - CHPAD * KPAD - CHPAD * 16;
        int r = j3 / CHPAD, c = j3 - r * CHPAD;
        float v = (r < NRBF && c < CAT) ? fw[r * CAT + c] : 0.f;
        unsigned short h = f32_bf16_rne(v);
        unsigned short l = f32_bf16_rne(v - bf16_f32(h));
        int wv = c >> 5, kk = c & 31;
        int lane = (kk >> 3) * 16 + r, j = kk & 7;
        size_t idx = ((size_t)wv * 64 + lane) * 16 + j;
        FwF[idx] = h; FwF[idx + 8] = l;
    }
}

// ---------------------------------------------------------------------------
// angle: s_a = dot(a_sbf[a,:], colsum(W_a)), scatter-add into sum_s[kj]
// ---------------------------------------------------------------------------
__global__ __launch_bounds__(256) void angle_kernel(
    const float* __restrict__ a_sbf, const int* __restrict__ kj_idx,
    const float* __restrict__ W_a, float* __restrict__ sum_s, int A)
{
    __shared__ float wsum[ADIM];
    int tid = threadIdx.x;
    if (tid < ADIM) {
        float s = 0.f;
        #pragma unroll
        for (int b = 0; b < NBIL; ++b) s += W_a[b * ADIM + tid];
        wsum[tid] = s;
    }
    __syncthreads();

    int a = blockIdx.x * 256 + tid;
    if (a >= A) return;

    const float* row = a_sbf + (size_t)a * ADIM;
    float s = 0.f;
    #pragma unroll
    for (int d2 = 0; d2 < ADIM / 2; ++d2) {
        float2 v = *reinterpret_cast<const float2*>(row + d2 * 2);
        s += v.x * wsum[d2 * 2] + v.y * wsum[d2 * 2 + 1];
    }
    atomicAdd(&sum_s[kj_idx[a]], s);
}

// Zero-instruction opaque pin: hi-only weight set (44 VGPRs).
#define PIN_WEIGHTS()                                                          \
    asm volatile("" :                                                         \
        "+v"(wfh[0]), "+v"(wfh[1]), "+v"(wfh[2]), "+v"(wfh[3]), "+v"(wfh[4]), \
        "+v"(wfh[5]), "+v"(wfh[6]), "+v"(wfh[7]), "+v"(wfh[8]),               \
        "+v"(weh), "+v"(fwh))

#define MF32(AC, W, B) AC = __builtin_amdgcn_mfma_f32_32x32x16_bf16(W, B, AC, 0, 0, 0)

// ---------------------------------------------------------------------------
// edge: R19 structure (pure-bf16 MFMA1, fast_silu, 3 waves/EU pinned,
// LDS 29.7 KB) with: e_rbf hi-only (1 less MFMA + no split), grid 768
// (exactly 3 resident blocks/CU, uniform 16-17 tiles/block).
// ---------------------------------------------------------------------------
__global__ __launch_bounds__(256)
__attribute__((amdgpu_waves_per_eu(3, 3)))
void edge_kernel(
    const float* __restrict__ m_ji, const float* __restrict__ e_rbf,
    const float* __restrict__ We_raw,
    const unsigned short* __restrict__ WF, const unsigned short* __restrict__ WeF,
    const unsigned short* __restrict__ FwF,
    const float* __restrict__ sum_s, float* __restrict__ out, int E, int NT)
{
    __shared__ unsigned short mhs[TE][MSTR];    //  9728 B
    __shared__ unsigned short maeh[TE][TSTR];   // 10752 B (proj overlaid)
    __shared__ unsigned short wf4s[9][64][8];   //  9216 B  -> 29696 B total

    const int tid = threadIdx.x;
    const int l   = tid & 63;
    const int wv  = __builtin_amdgcn_readfirstlane(tid >> 6);  // 0..3
    const int l31 = l & 31;
    const int hi5 = l >> 5;
    const int GD  = gridDim.x;

    // ---- resident HI weight fragments for this wave's main group ---------
    bf16x8 wfh[9];
    #pragma unroll
    for (int ks = 0; ks < 9; ++ks)
        wfh[ks] = *reinterpret_cast<const bf16x8*>(WF + ((size_t)(wv * 9 + ks) * 64 + l) * 16);
    bf16x8 weh = *reinterpret_cast<const bf16x8*>(WeF + ((size_t)wv * 64 + l) * 16);
    bf16x8 fwh = *reinterpret_cast<const bf16x8*>(FwF + ((size_t)wv * 64 + l) * 16);
    PIN_WEIGHTS();

    // ---- stage tail group-4 HI A-fragments into LDS (once) ---------------
    {
        for (int f = tid; f < 9 * 64; f += 256) {   // 576 x 16B (hi half only)
            int ks = f / 64, ln = f - ks * 64;
            const uint4* src = reinterpret_cast<const uint4*>(
                WF + ((size_t)(4 * 9 + ks) * 64 + ln) * 16);
            *reinterpret_cast<uint4*>(&wf4s[ks][ln][0]) = src[0];
        }
    }

    // ---- wave-uniform W_e scalars for tail te (rows 128..133) -> SGPRs ---
    float we4[6][6];
    #pragma unroll
    for (int r0 = 0; r0 < 6; ++r0)
        #pragma unroll
        for (int r = 0; r < 6; ++r)
            we4[r0][r] = We_raw[(size_t)(128 + r0) * NRBF + r];

    // ---- one-time LDS init: m bias/pad cols 134..143 ---------------------
    if (tid < 160) {
        int r = tid / 5, j = tid - r * 5;
        *reinterpret_cast<unsigned*>(&mhs[r][134 + 2 * j]) = (j == 0) ? 0x00003F80u : 0u;
    }

    // ---- per-lane prefetch state -----------------------------------------
    float2 mpre[9];
    float2 er01, er23, er45;
    float  ssp;

#define LOADM(T)                                                              \
    do { int tt = (T);                                                        \
        const float2* mb = reinterpret_cast<const float2*>(m_ji + (size_t)tt * TE * CAT); \
        int nv2 = min(TE, E - tt * TE) * 67;                                  \
        _Pragma("unroll")                                                     \
        for (int i_ = 0; i_ < 9; ++i_) {                                      \
            int f_ = tid + i_ * 256;                                          \
            mpre[i_] = (f_ < nv2) ? mb[f_] : make_float2(0.f, 0.f);           \
        }                                                                     \
    } while (0)

#define LOADE(T)                                                              \
    do { int tt = (T);                                                        \
        er01 = make_float2(0.f, 0.f); er23 = er01; er45 = er01;               \
        int e_ = tt * TE + l31;                                               \
        if (e_ < E) {                                                         \
            const float* ep_ = e_rbf + (size_t)e_ * NRBF;                     \
            er01 = *reinterpret_cast<const float2*>(ep_);                     \
            er23 = *reinterpret_cast<const float2*>(ep_ + 2);                 \
            er45 = *reinterpret_cast<const float2*>(ep_ + 4);                 \
        }                                                                     \
    } while (0)

#define LOADSS(T)                                                             \
    do { int tt = (T);                                                        \
        ssp = 0.f;                                                            \
        if (tid < 192) {                                                      \
            int eo_ = tt * TE + tid / 6;                                      \
            if (eo_ < E) ssp = sum_s[eo_];                                    \
        }                                                                     \
    } while (0)

    // ---- prologue: prefetch tile t0 ---------------------------------------
    {
        int t0 = blockIdx.x;
        LOADM(t0); LOADE(t0); LOADSS(t0);
    }

    int it = 0;
    for (int t = blockIdx.x; t < NT; t += GD, ++it) {
        const int e0 = t * TE;
        PIN_WEIGHTS();

        // ---- latch this tile's er (tail te) + ss; build eb frag (hi) -----
        float er_s0 = er01.x, er_s1 = er01.y, er_s2 = er23.x,
              er_s3 = er23.y, er_s4 = er45.x, er_s5 = er45.y;
        const float ss_cur = ssp;
        bf16x8 ebh;
        {
            unsigned h0 = 0, h1 = 0, h2 = 0;
            if (!hi5) {   // k 8..15 pad on hi half
                h0 = rne_pack(er01.x, er01.y);
                h1 = rne_pack(er23.x, er23.y);
                h2 = rne_pack(er45.x, er45.y);
            }
            ebh = upack(h0, h1, h2, 0);
        }

        // ---- stage m tile -> RNE bf16 LDS (hi only) ----------------------
        #pragma unroll
        for (int i = 0; i < 9; ++i) {
            int f = tid + i * 256;
            if (f < M2) {
                int r = f / 67, c = f - r * 67;
                *reinterpret_cast<unsigned*>(&mhs[r][2 * c]) = rne_pack(mpre[i].x, mpre[i].y);
            }
        }
        __syncthreads();   // barrier A: tile staged

        // ---- issue next tile's global loads (ride under MFMA) ------------
        if (t + GD < NT) { LOADM(t + GD); LOADE(t + GD); LOADSS(t + GD); }

        // ---- MFMA1 main: x = Wh.mh (+bias), 9 MFMAs ----------------------
        f32x16 acc  = {0,0,0,0,0,0,0,0,0,0,0,0,0,0,0,0};
        f32x16 acct = {0,0,0,0,0,0,0,0,0,0,0,0,0,0,0,0};
        #pragma unroll
        for (int ks = 0; ks < 9; ++ks) {
            bf16x8 bh = *reinterpret_cast<const bf16x8*>(&mhs[l31][ks * 16 + hi5 * 8]);
            MF32(acc, wfh[ks], bh);
        }
        MF32(acct, weh, ebh);

        // ---- mae = silu(x)*te -> RNE bf16 -> wave-private LDS slice ------
        #pragma unroll
        for (int q = 0; q < 4; ++q) {
            float mz[4];
            #pragma unroll
            for (int i = 0; i < 4; ++i)
                mz[i] = fast_silu(acc[q * 4 + i]) * acct[q * 4 + i];
            const int cq = 32 * wv + 8 * q + 4 * hi5;
            *reinterpret_cast<uint2*>(&maeh[l31][cq]) =
                make_uint2(rne_pack(mz[0], mz[1]), rne_pack(mz[2], mz[3]));
        }

        // ---- MFMA3 main: own slice -> overlay [es][32wv..], 1 MFMA/nt ----
        #pragma unroll
        for (int nt = 0; nt < 2; ++nt) {
            f32x4 a3 = {0, 0, 0, 0};
            const int mr = nt * 16 + (l & 15);
            bf16x8 bh = *reinterpret_cast<const bf16x8*>(&maeh[mr][32 * wv + (l >> 4) * 8]);
            a3 = __builtin_amdgcn_mfma_f32_16x16x32_bf16(fwh, bh, a3, 0, 0, 0);
            const int g4 = l >> 4, es = nt * 16 + (l & 15);
            if (g4 == 0) {
                *reinterpret_cast<f32x4*>(&maeh[es][32 * wv]) = a3;
            } else if (g4 == 1) {
                *reinterpret_cast<float*>(&maeh[es][32 * wv + 8])  = a3[0];
                *reinterpret_cast<float*>(&maeh[es][32 * wv + 10]) = a3[1];
            }
        }

        // ---- TAIL group 4 (channels 128-133), one rotating wave ----------
        if (wv == ((blockIdx.x + it) & 3)) {
            const unsigned short* pf4 = FwF + ((size_t)4 * 64 + l) * 16;
            bf16x8 fw4h = *reinterpret_cast<const bf16x8*>(pf4);

            f32x16 acc4 = {0,0,0,0,0,0,0,0,0,0,0,0,0,0,0,0};
            #pragma unroll
            for (int ks = 0; ks < 9; ++ks) {   // A-frags from LDS (pipelined)
                bf16x8 a4h = *reinterpret_cast<const bf16x8*>(&wf4s[ks][l][0]);
                bf16x8 bh = *reinterpret_cast<const bf16x8*>(&mhs[l31][ks * 16 + hi5 * 8]);
                MF32(acc4, a4h, bh);
            }
            // te4 in fp32 VALU: reg i covers row (i&3)+8(i>>2)+4hi5
            float te4[4];
            #pragma unroll
            for (int i = 0; i < 4; ++i) {
                float dlo = er_s0 * we4[i][0] + er_s1 * we4[i][1] + er_s2 * we4[i][2]
                          + er_s3 * we4[i][3] + er_s4 * we4[i][4] + er_s5 * we4[i][5];
                float dhi = 0.f;
                if (i < 2)
                    dhi = er_s0 * we4[4 + i][0] + er_s1 * we4[4 + i][1] + er_s2 * we4[4 + i][2]
                        + er_s3 * we4[4 + i][3] + er_s4 * we4[4 + i][4] + er_s5 * we4[4 + i][5];
                te4[i] = hi5 ? dhi : dlo;
            }
            // mae4 (hi only; rows 0-5 live in q==0 regs)
            {
                float mz[4];
                #pragma unroll
                for (int i = 0; i < 4; ++i)
                    mz[i] = fast_silu(acc4[i]) * te4[i];
                const int cq = 128 + 4 * hi5;
                *reinterpret_cast<uint2*>(&maeh[l31][cq]) =
                    make_uint2(rne_pack(mz[0], mz[1]), rne_pack(mz[2], mz[3]));
                #pragma unroll
                for (int q = 1; q < 4; ++q)
                    *reinterpret_cast<uint2*>(&maeh[l31][128 + 8 * q + 4 * hi5]) = make_uint2(0, 0);
            }
            // tail MFMA3 -> overlay [es][128..]
            #pragma unroll
            for (int nt = 0; nt < 2; ++nt) {
                f32x4 a3 = {0, 0, 0, 0};
                const int mr = nt * 16 + (l & 15);
                bf16x8 bh = *reinterpret_cast<const bf16x8*>(&maeh[mr][128 + (l >> 4) * 8]);
                a3 = __builtin_amdgcn_mfma_f32_16x16x32_bf16(fw4h, bh, a3, 0, 0, 0);
                const int g4 = l >> 4, es = nt * 16 + (l & 15);
                if (g4 == 0) {
                    *reinterpret_cast<f32x4*>(&maeh[es][128]) = a3;
                } else if (g4 == 1) {
                    *reinterpret_cast<float*>(&maeh[es][128 + 8])  = a3[0];
                    *reinterpret_cast<float*>(&maeh[es][128 + 10]) = a3[1];
                }
            }
        }
        __syncthreads();   // barrier B: all overlays complete

        // ---- cross-group reduce + scale + store --------------------------
        if (tid < 192) {
            const int es = tid / 6, r = tid - es * 6;
            const int eo = e0 + es;
            if (eo < E) {
                float vsum = 0.f;
                #pragma unroll
                for (int w2 = 0; w2 < 5; ++w2)
                    vsum += *reinterpret_cast<const float*>(&maeh[es][32 * w2 + 2 * r]);
                out[(size_t)eo * NRBF + r] = vsum * ss_cur;
            }
        }
    }
#undef LOADM
#undef LOADE
#undef LOADSS
}

// ---------------------------------------------------------------------------
extern "C" void kernel_launch(void* const* d_in, const int* in_sizes, int n_in,
                              void* d_out, int out_size, void* d_ws, size_t ws_size,
                              hipStream_t stream)
{
    const float* m_ji    = (const float*)d_in[0];
    // d_in[1] nbr_list, d_in[2] angle_list: unused by the reference math
    const float* e_rbf   = (const float*)d_in[3];
    const float* a_sbf   = (const float*)d_in[4];
    const int*   kj_idx  = (const int*)  d_in[5];
    const float* W_m     = (const float*)d_in[6];
    const float* b_m     = (const float*)d_in[7];
    const float* W_e     = (const float*)d_in[8];
    const float* W_a     = (const float*)d_in[9];
    const float* final_w = (const float*)d_in[10];
    float* out = (float*)d_out;

    const int E  = in_sizes[0] / CAT;
    const int A  = in_sizes[5];
    const int NT = (E + TE - 1) / TE;

    // workspace layout
    char* ws = (char*)d_ws;
    float* sum_s = (float*)ws;
    size_t off = ((size_t)E * 4 + 255) & ~(size_t)255;
    unsigned short* WF  = (unsigned short*)(ws + off); off += (size_t)5 * 9 * 64 * 16 * 2;
    unsigned short* WeF = (unsigned short*)(ws + off); off += (size_t)5 * 64 * 16 * 2;
    unsigned short* FwF = (unsigned short*)(ws + off); off += (size_t)5 * 64 * 16 * 2;

    const int prep_n = CHPAD * KPAD + CHPAD * 16 + 16 * CHPAD;
    int prep_grid = (E > prep_n ? E : prep_n);
    prep_kernel<<<(prep_grid + 255) / 256, 256, 0, stream>>>(
        W_m, b_m, W_e, final_w, WF, WeF, FwF, sum_s, E);
    angle_kernel<<<(A + 255) / 256, 256, 0, stream>>>(a_sbf, kj_idx, W_a, sum_s, A);

    int grid = 768; if (grid > NT) grid = NT;
    edge_kernel<<<grid, 256, 0, stream>>>(m_ji, e_rbf, W_e, WF, WeF, FwF,
                                          sum_s, out, E, NT);
}

// Round 21
// 113.513 us; speedup vs baseline: 1.7552x; 1.0044x over previous
//
#include <hip/hip_runtime.h>
#include <math.h>

#define CAT    134
#define NRBF   6
#define ADIM   42
#define NBIL   8
#define KPAD   144      // 9 k-steps of 16 (k=134 is the bias column)
#define CHPAD  160      // 5 groups x 32 channels
#define MSTR   152      // m LDS row stride (shorts): 304 B, 16B-aligned
#define TSTR   168      // mae row stride (shorts): 336 B, 16B-aligned
#define TE     32       // edges per tile
#define M2     (TE * 67)   // float2 count of one m tile (32*134/2)

typedef __bf16 bf16x8 __attribute__((ext_vector_type(8)));
typedef float  f32x16 __attribute__((ext_vector_type(16)));
typedef float  f32x4  __attribute__((ext_vector_type(4)));

__device__ __forceinline__ unsigned short f32_bf16_rne(float x) {
    union { float f; unsigned u; } v; v.f = x;
    unsigned u = v.u;
    u += 0x7FFFu + ((u >> 16) & 1u);
    return (unsigned short)(u >> 16);
}
__device__ __forceinline__ float bf16_f32(unsigned short h) {
    union { float f; unsigned u; } v; v.u = ((unsigned)h) << 16;
    return v.f;
}
// RNE pack of two floats to a bf16 pair
__device__ __forceinline__ unsigned rne_pack(float a, float b) {
    return (unsigned)f32_bf16_rne(a) | ((unsigned)f32_bf16_rne(b) << 16);
}
__device__ __forceinline__ bf16x8 upack(unsigned a, unsigned b, unsigned c, unsigned d) {
    union { unsigned u[4]; bf16x8 v; } t;
    t.u[0] = a; t.u[1] = b; t.u[2] = c; t.u[3] = d;
    return t.v;
}
// fast silu: x * rcp(1+exp(-x)) -- avoids the IEEE fp32 divide sequence.
__device__ __forceinline__ float fast_silu(float x) {
    return x * __builtin_amdgcn_rcpf(1.f + __expf(-x));
}

// ---------------------------------------------------------------------------
// prep: pack weights into FRAGMENT-MAJOR layout (hi+lo; kernel reads hi only)
// + zero sum_s (replaces the hipMemsetAsync graph node)
// ---------------------------------------------------------------------------
__global__ __launch_bounds__(256) void prep_kernel(
    const float* __restrict__ Wm, const float* __restrict__ bm,
    const float* __restrict__ We, const float* __restrict__ fw,
    unsigned short* __restrict__ WF, unsigned short* __restrict__ WeF,
    unsigned short* __restrict__ FwF, float* __restrict__ sum_s, int E)
{
    int i = blockIdx.x * 256 + threadIdx.x;
    if (i < E) sum_s[i] = 0.f;
    if (i < CHPAD * KPAD) {                                  // W_m (+bias col)
        int c = i / KPAD, k = i - c * KPAD;
        float v = 0.f;
        if (c < CAT) {
            if (k < CAT) v = Wm[c * CAT + k];
            else if (k == CAT) v = bm[c];
        }
        unsigned short h = f32_bf16_rne(v);
        unsigned short l = f32_bf16_rne(v - bf16_f32(h));
        int wv = c >> 5, l31 = c & 31, ks = k >> 4;
        int lane = ((k >> 3) & 1) * 32 + l31, j = k & 7;
        size_t idx = ((size_t)(wv * 9 + ks) * 64 + lane) * 16 + j;
        WF[idx] = h; WF[idx + 8] = l;
    } else if (i < CHPAD * KPAD + CHPAD * 16) {              // W_e (K -> 16)
        int j2 = i - CHPAD * KPAD; int c = j2 >> 4, r = j2 & 15;
        float v = (c < CAT && r < NRBF) ? We[c * NRBF + r] : 0.f;
        unsigned short h = f32_bf16_rne(v);
        unsigned short l = f32_bf16_rne(v - bf16_f32(h));
        int wv = c >> 5, l31 = c & 31;
        int lane = (r >> 3) * 32 + l31, j = r & 7;
        size_t idx = ((size_t)wv * 64 + lane) * 16 + j;
        WeF[idx] = h; WeF[idx + 8] = l;
    } else if (i < CHPAD * KPAD + CHPAD * 16 + 16 * CHPAD) { // final_w (16 rows)
        int j3 = i - CHPAD * KPAD - CHPAD * 16;
        int r = j3 / CHPAD, c = j3 - r * CHPAD;
        float v = (r < NRBF && c < CAT) ? fw[r * CAT + c] : 0.f;
        unsigned short h = f32_bf16_rne(v);
        unsigned short l = f32_bf16_rne(v - bf16_f32(h));
        int wv = c >> 5, kk = c & 31;
        int lane = (kk >> 3) * 16 + r, j = kk & 7;
        size_t idx = ((size_t)wv * 64 + lane) * 16 + j;
        FwF[idx] = h; FwF[idx + 8] = l;
    }
}

// ---------------------------------------------------------------------------
// angle: s_a = dot(a_sbf[a,:], colsum(W_a)), scatter-add into sum_s[kj]
// ---------------------------------------------------------------------------
__global__ __launch_bounds__(256) void angle_kernel(
    const float* __restrict__ a_sbf, const int* __restrict__ kj_idx,
    const float* __restrict__ W_a, float* __restrict__ sum_s, int A)
{
    __shared__ float wsum[ADIM];
    int tid = threadIdx.x;
    if (tid < ADIM) {
        float s = 0.f;
        #pragma unroll
        for (int b = 0; b < NBIL; ++b) s += W_a[b * ADIM + tid];
        wsum[tid] = s;
    }
    __syncthreads();

    int a = blockIdx.x * 256 + tid;
    if (a >= A) return;

    const float* row = a_sbf + (size_t)a * ADIM;
    float s = 0.f;
    #pragma unroll
    for (int d2 = 0; d2 < ADIM / 2; ++d2) {
        float2 v = *reinterpret_cast<const float2*>(row + d2 * 2);
        s += v.x * wsum[d2 * 2] + v.y * wsum[d2 * 2 + 1];
    }
    atomicAdd(&sum_s[kj_idx[a]], s);
}

// Zero-instruction opaque pin: hi-only weight set (44 VGPRs).
#define PIN_WEIGHTS()                                                          \
    asm volatile("" :                                                         \
        "+v"(wfh[0]), "+v"(wfh[1]), "+v"(wfh[2]), "+v"(wfh[3]), "+v"(wfh[4]), \
        "+v"(wfh[5]), "+v"(wfh[6]), "+v"(wfh[7]), "+v"(wfh[8]),               \
        "+v"(weh), "+v"(fwh))

#define MF32(AC, W, B) AC = __builtin_amdgcn_mfma_f32_32x32x16_bf16(W, B, AC, 0, 0, 0)

// ---------------------------------------------------------------------------
// edge: R19 structure (pure-bf16 MFMA1, fast_silu, 3 waves/EU pinned,
// LDS 29.7 KB) with: e_rbf hi-only (1 less MFMA + no split), grid 768
// (exactly 3 resident blocks/CU, uniform 16-17 tiles/block).
// ---------------------------------------------------------------------------
__global__ __launch_bounds__(256)
__attribute__((amdgpu_waves_per_eu(3, 3)))
void edge_kernel(
    const float* __restrict__ m_ji, const float* __restrict__ e_rbf,
    const float* __restrict__ We_raw,
    const unsigned short* __restrict__ WF, const unsigned short* __restrict__ WeF,
    const unsigned short* __restrict__ FwF,
    const float* __restrict__ sum_s, float* __restrict__ out, int E, int NT)
{
    __shared__ unsigned short mhs[TE][MSTR];    //  9728 B
    __shared__ unsigned short maeh[TE][TSTR];   // 10752 B (proj overlaid)
    __shared__ unsigned short wf4s[9][64][8];   //  9216 B  -> 29696 B total

    const int tid = threadIdx.x;
    const int l   = tid & 63;
    const int wv  = __builtin_amdgcn_readfirstlane(tid >> 6);  // 0..3
    const int l31 = l & 31;
    const int hi5 = l >> 5;
    const int GD  = gridDim.x;

    // ---- resident HI weight fragments for this wave's main group ---------
    bf16x8 wfh[9];
    #pragma unroll
    for (int ks = 0; ks < 9; ++ks)
        wfh[ks] = *reinterpret_cast<const bf16x8*>(WF + ((size_t)(wv * 9 + ks) * 64 + l) * 16);
    bf16x8 weh = *reinterpret_cast<const bf16x8*>(WeF + ((size_t)wv * 64 + l) * 16);
    bf16x8 fwh = *reinterpret_cast<const bf16x8*>(FwF + ((size_t)wv * 64 + l) * 16);
    PIN_WEIGHTS();

    // ---- stage tail group-4 HI A-fragments into LDS (once) ---------------
    {
        for (int f = tid; f < 9 * 64; f += 256) {   // 576 x 16B (hi half only)
            int ks = f / 64, ln = f - ks * 64;
            const uint4* src = reinterpret_cast<const uint4*>(
                WF + ((size_t)(4 * 9 + ks) * 64 + ln) * 16);
            *reinterpret_cast<uint4*>(&wf4s[ks][ln][0]) = src[0];
        }
    }

    // ---- wave-uniform W_e scalars for tail te (rows 128..133) -> SGPRs ---
    float we4[6][6];
    #pragma unroll
    for (int r0 = 0; r0 < 6; ++r0)
        #pragma unroll
        for (int r = 0; r < 6; ++r)
            we4[r0][r] = We_raw[(size_t)(128 + r0) * NRBF + r];

    // ---- one-time LDS init: m bias/pad cols 134..143 ---------------------
    if (tid < 160) {
        int r = tid / 5, j = tid - r * 5;
        *reinterpret_cast<unsigned*>(&mhs[r][134 + 2 * j]) = (j == 0) ? 0x00003F80u : 0u;
    }

    // ---- per-lane prefetch state -----------------------------------------
    float2 mpre[9];
    float2 er01, er23, er45;
    float  ssp;

#define LOADM(T)                                                              \
    do { int tt = (T);                                                        \
        const float2* mb = reinterpret_cast<const float2*>(m_ji + (size_t)tt * TE * CAT); \
        int nv2 = min(TE, E - tt * TE) * 67;                                  \
        _Pragma("unroll")                                                     \
        for (int i_ = 0; i_ < 9; ++i_) {                                      \
            int f_ = tid + i_ * 256;                                          \
            mpre[i_] = (f_ < nv2) ? mb[f_] : make_float2(0.f, 0.f);           \
        }                                                                     \
    } while (0)

#define LOADE(T)                                                              \
    do { int tt = (T);                                                        \
        er01 = make_float2(0.f, 0.f); er23 = er01; er45 = er01;               \
        int e_ = tt * TE + l31;                                               \
        if (e_ < E) {                                                         \
            const float* ep_ = e_rbf + (size_t)e_ * NRBF;                     \
            er01 = *reinterpret_cast<const float2*>(ep_);                     \
            er23 = *reinterpret_cast<const float2*>(ep_ + 2);                 \
            er45 = *reinterpret_cast<const float2*>(ep_ + 4);                 \
        }                                                                     \
    } while (0)

#define LOADSS(T)                                                             \
    do { int tt = (T);                                                        \
        ssp = 0.f;                                                            \
        if (tid < 192) {                                                      \
            int eo_ = tt * TE + tid / 6;                                      \
            if (eo_ < E) ssp = sum_s[eo_];                                    \
        }                                                                     \
    } while (0)

    // ---- prologue: prefetch tile t0 ---------------------------------------
    {
        int t0 = blockIdx.x;
        LOADM(t0); LOADE(t0); LOADSS(t0);
    }

    int it = 0;
    for (int t = blockIdx.x; t < NT; t += GD, ++it) {
        const int e0 = t * TE;
        PIN_WEIGHTS();

        // ---- latch this tile's er (tail te) + ss; build eb frag (hi) -----
        float er_s0 = er01.x, er_s1 = er01.y, er_s2 = er23.x,
              er_s3 = er23.y, er_s4 = er45.x, er_s5 = er45.y;
        const float ss_cur = ssp;
        bf16x8 ebh;
        {
            unsigned h0 = 0, h1 = 0, h2 = 0;
            if (!hi5) {   // k 8..15 pad on hi half
                h0 = rne_pack(er01.x, er01.y);
                h1 = rne_pack(er23.x, er23.y);
                h2 = rne_pack(er45.x, er45.y);
            }
            ebh = upack(h0, h1, h2, 0);
        }

        // ---- stage m tile -> RNE bf16 LDS (hi only) ----------------------
        #pragma unroll
        for (int i = 0; i < 9; ++i) {
            int f = tid + i * 256;
            if (f < M2) {
                int r = f / 67, c = f - r * 67;
                *reinterpret_cast<unsigned*>(&mhs[r][2 * c]) = rne_pack(mpre[i].x, mpre[i].y);
            }
        }
        __syncthreads();   // barrier A: tile staged

        // ---- issue next tile's global loads (ride under MFMA) ------------
        if (t + GD < NT) { LOADM(t + GD); LOADE(t + GD); LOADSS(t + GD); }

        // ---- MFMA1 main: x = Wh.mh (+bias), 9 MFMAs ----------------------
        f32x16 acc  = {0,0,0,0,0,0,0,0,0,0,0,0,0,0,0,0};
        f32x16 acct = {0,0,0,0,0,0,0,0,0,0,0,0,0,0,0,0};
        #pragma unroll
        for (int ks = 0; ks < 9; ++ks) {
            bf16x8 bh = *reinterpret_cast<const bf16x8*>(&mhs[l31][ks * 16 + hi5 * 8]);
            MF32(acc, wfh[ks], bh);
        }
        MF32(acct, weh, ebh);

        // ---- mae = silu(x)*te -> RNE bf16 -> wave-private LDS slice ------
        #pragma unroll
        for (int q = 0; q < 4; ++q) {
            float mz[4];
            #pragma unroll
            for (int i = 0; i < 4; ++i)
                mz[i] = fast_silu(acc[q * 4 + i]) * acct[q * 4 + i];
            const int cq = 32 * wv + 8 * q + 4 * hi5;
            *reinterpret_cast<uint2*>(&maeh[l31][cq]) =
                make_uint2(rne_pack(mz[0], mz[1]), rne_pack(mz[2], mz[3]));
        }

        // ---- MFMA3 main: own slice -> overlay [es][32wv..], 1 MFMA/nt ----
        #pragma unroll
        for (int nt = 0; nt < 2; ++nt) {
            f32x4 a3 = {0, 0, 0, 0};
            const int mr = nt * 16 + (l & 15);
            bf16x8 bh = *reinterpret_cast<const bf16x8*>(&maeh[mr][32 * wv + (l >> 4) * 8]);
            a3 = __builtin_amdgcn_mfma_f32_16x16x32_bf16(fwh, bh, a3, 0, 0, 0);
            const int g4 = l >> 4, es = nt * 16 + (l & 15);
            if (g4 == 0) {
                *reinterpret_cast<f32x4*>(&maeh[es][32 * wv]) = a3;
            } else if (g4 == 1) {
                *reinterpret_cast<float*>(&maeh[es][32 * wv + 8])  = a3[0];
                *reinterpret_cast<float*>(&maeh[es][32 * wv + 10]) = a3[1];
            }
        }

        // ---- TAIL group 4 (channels 128-133), one rotating wave ----------
        if (wv == ((blockIdx.x + it) & 3)) {
            const unsigned short* pf4 = FwF + ((size_t)4 * 64 + l) * 16;
            bf16x8 fw4h = *reinterpret_cast<const bf16x8*>(pf4);

            f32x16 acc4 = {0,0,0,0,0,0,0,0,0,0,0,0,0,0,0,0};
            #pragma unroll
            for (int ks = 0; ks < 9; ++ks) {   // A-frags from LDS (pipelined)
                bf16x8 a4h = *reinterpret_cast<const bf16x8*>(&wf4s[ks][l][0]);
                bf16x8 bh = *reinterpret_cast<const bf16x8*>(&mhs[l31][ks * 16 + hi5 * 8]);
                MF32(acc4, a4h, bh);
            }
            // te4 in fp32 VALU: reg i covers row (i&3)+8(i>>2)+4hi5
            float te4[4];
            #pragma unroll
            for (int i = 0; i < 4; ++i) {
                float dlo = er_s0 * we4[i][0] + er_s1 * we4[i][1] + er_s2 * we4[i][2]
                          + er_s3 * we4[i][3] + er_s4 * we4[i][4] + er_s5 * we4[i][5];
                float dhi = 0.f;
                if (i < 2)
                    dhi = er_s0 * we4[4 + i][0] + er_s1 * we4[4 + i][1] + er_s2 * we4[4 + i][2]
                        + er_s3 * we4[4 + i][3] + er_s4 * we4[4 + i][4] + er_s5 * we4[4 + i][5];
                te4[i] = hi5 ? dhi : dlo;
            }
            // mae4 (hi only; rows 0-5 live in q==0 regs)
            {
                float mz[4];
                #pragma unroll
                for (int i = 0; i < 4; ++i)
                    mz[i] = fast_silu(acc4[i]) * te4[i];
                const int cq = 128 + 4 * hi5;
                *reinterpret_cast<uint2*>(&maeh[l31][cq]) =
                    make_uint2(rne_pack(mz[0], mz[1]), rne_pack(mz[2], mz[3]));
                #pragma unroll
                for (int q = 1; q < 4; ++q)
                    *reinterpret_cast<uint2*>(&maeh[l31][128 + 8 * q + 4 * hi5]) = make_uint2(0, 0);
            }
            // tail MFMA3 -> overlay [es][128..]
            #pragma unroll
            for (int nt = 0; nt < 2; ++nt) {
                f32x4 a3 = {0, 0, 0, 0};
                const int mr = nt * 16 + (l & 15);
                bf16x8 bh = *reinterpret_cast<const bf16x8*>(&maeh[mr][128 + (l >> 4) * 8]);
                a3 = __builtin_amdgcn_mfma_f32_16x16x32_bf16(fw4h, bh, a3, 0, 0, 0);
                const int g4 = l >> 4, es = nt * 16 + (l & 15);
                if (g4 == 0) {
                    *reinterpret_cast<f32x4*>(&maeh[es][128]) = a3;
                } else if (g4 == 1) {
                    *reinterpret_cast<float*>(&maeh[es][128 + 8])  = a3[0];
                    *reinterpret_cast<float*>(&maeh[es][128 + 10]) = a3[1];
                }
            }
        }
        __syncthreads();   // barrier B: all overlays complete

        // ---- cross-group reduce + scale + store --------------------------
        if (tid < 192) {
            const int es = tid / 6, r = tid - es * 6;
            const int eo = e0 + es;
            if (eo < E) {
                float vsum = 0.f;
                #pragma unroll
                for (int w2 = 0; w2 < 5; ++w2)
                    vsum += *reinterpret_cast<const float*>(&maeh[es][32 * w2 + 2 * r]);
                out[(size_t)eo * NRBF + r] = vsum * ss_cur;
            }
        }
    }
#undef LOADM
#undef LOADE
#undef LOADSS
}

// ---------------------------------------------------------------------------
extern "C" void kernel_launch(void* const* d_in, const int* in_sizes, int n_in,
                              void* d_out, int out_size, void* d_ws, size_t ws_size,
                              hipStream_t stream)
{
    const float* m_ji    = (const float*)d_in[0];
    // d_in[1] nbr_list, d_in[2] angle_list: unused by the reference math
    const float* e_rbf   = (const float*)d_in[3];
    const float* a_sbf   = (const float*)d_in[4];
    const int*   kj_idx  = (const int*)  d_in[5];
    const float* W_m     = (const float*)d_in[6];
    const float* b_m     = (const float*)d_in[7];
    const float* W_e     = (const float*)d_in[8];
    const float* W_a     = (const float*)d_in[9];
    const float* final_w = (const float*)d_in[10];
    float* out = (float*)d_out;

    const int E  = in_sizes[0] / CAT;
    const int A  = in_sizes[5];
    const int NT = (E + TE - 1) / TE;

    // workspace layout
    char* ws = (char*)d_ws;
    float* sum_s = (float*)ws;
    size_t off = ((size_t)E * 4 + 255) & ~(size_t)255;
    unsigned short* WF  = (unsigned short*)(ws + off); off += (size_t)5 * 9 * 64 * 16 * 2;
    unsigned short* WeF = (unsigned short*)(ws + off); off += (size_t)5 * 64 * 16 * 2;
    unsigned short* FwF = (unsigned short*)(ws + off); off += (size_t)5 * 64 * 16 * 2;

    const int prep_n = CHPAD * KPAD + CHPAD * 16 + 16 * CHPAD;
    int prep_grid = (E > prep_n ? E : prep_n);
    prep_kernel<<<(prep_grid + 255) / 256, 256, 0, stream>>>(
        W_m, b_m, W_e, final_w, WF, WeF, FwF, sum_s, E);
    angle_kernel<<<(A + 255) / 256, 256, 0, stream>>>(a_sbf, kj_idx, W_a, sum_s, A);

    int grid = 768; if (grid > NT) grid = NT;
    edge_kernel<<<grid, 256, 0, stream>>>(m_ji, e_rbf, W_e, WF, WeF, FwF,
                                          sum_s, out, E, NT);
}